// Round 7
// baseline (2120.014 us; speedup 1.0000x reference)
//
#include <hip/hip_runtime.h>
#include <math.h>

#define NB 8
#define NP 4096
#define NCIN 64
#define NS 1024
#define NK 32
#define NC 128
#define NJ 5
#define NDEPTH 2
#define NH 4
#define NPTS (NB*NS)       /* 8192 groups */
#define NM (NPTS*NK)       /* 262144 rows */
#define EPSF 1e-5f

typedef float f32x4 __attribute__((ext_vector_type(4)));
typedef short bf16x8 __attribute__((ext_vector_type(8)));
typedef unsigned short ushort_t;
typedef unsigned long long u64;

#define MFMA(a,b,c) __builtin_amdgcn_mfma_f32_16x16x32_bf16(a,b,c,0,0,0)

__device__ __forceinline__ ushort_t f2b(float f) {
  unsigned int u = __float_as_uint(f);
  u = (u + 0x7fffu + ((u >> 16) & 1u)) >> 16;
  return (ushort_t)u;
}
__device__ __forceinline__ float b2f(ushort_t h) {
  unsigned int u = ((unsigned int)h) << 16;
  return __uint_as_float(u);
}

// DPP in-row-of-16 reduce (VALU pipe). quad_perm xor1=0xB1, xor2=0x4E,
// row_half_mirror=0x141 (combines quads in 8), row_mirror=0x140 (combines 8s).
template<int CTRL>
__device__ __forceinline__ float dpp_f(float v) {
  return __int_as_float(__builtin_amdgcn_update_dpp(0, __float_as_int(v), CTRL, 0xf, 0xf, true));
}
__device__ __forceinline__ float dpp_sum16(float v) {
  v += dpp_f<0xB1>(v); v += dpp_f<0x4E>(v);
  v += dpp_f<0x141>(v); v += dpp_f<0x140>(v);
  return v;
}
__device__ __forceinline__ float dpp_max16(float v) {
  v = fmaxf(v, dpp_f<0xB1>(v)); v = fmaxf(v, dpp_f<0x4E>(v));
  v = fmaxf(v, dpp_f<0x141>(v)); v = fmaxf(v, dpp_f<0x140>(v));
  return v;
}

// ---------------------------------------------------------------- FPS
#define DPPMAX(CTRL) { \
  unsigned lo2 = (unsigned)__builtin_amdgcn_update_dpp(0, (int)(unsigned)best, CTRL, 0xf, 0xf, true); \
  unsigned hi2 = (unsigned)__builtin_amdgcn_update_dpp(0, (int)(unsigned)(best >> 32), CTRL, 0xf, 0xf, true); \
  u64 o = ((u64)hi2 << 32) | lo2; \
  if (o > best) best = o; }

__global__ __launch_bounds__(256) void k_fps(const float* __restrict__ xyz,
                                             float* __restrict__ newxyz) {
  const int b = blockIdx.x;
  const int t = threadIdx.x;
  const int lane = t & 63;
  const int w = t >> 6;
  __shared__ float Xl[NP*3];
  __shared__ float cenL[NS*3];
  __shared__ u64 slotP[2][4];
  __shared__ __align__(16) float slotC[2][4][4];   // winner coords per wave
  const float* X = xyz + (size_t)b * NP * 3;
  for (int i = t; i < NP*3; i += 256) Xl[i] = X[i];
  __syncthreads();
  float px[16], py[16], pz[16], dist[16];
  unsigned inv[16];
#pragma unroll
  for (int i = 0; i < 16; ++i) {
    int n = t + 256*i;
    px[i] = Xl[3*n]; py[i] = Xl[3*n+1]; pz[i] = Xl[3*n+2];
    dist[i] = 1e10f;
    inv[i] = ~(unsigned)n;
  }
  float cx = Xl[0], cy = Xl[1], cz = Xl[2];   // far = 0 initially
  for (int s = 0; s < NS; ++s) {
    if (t == 0) { cenL[3*s] = cx; cenL[3*s+1] = cy; cenL[3*s+2] = cz; }
    u64 pk[16];
#pragma unroll
    for (int i = 0; i < 16; ++i) {
      float dx = px[i]-cx, dy = py[i]-cy, dz = pz[i]-cz;
      float d = fmaf(dx,dx, fmaf(dy,dy, dz*dz));
      float nd = fminf(dist[i], d);
      dist[i] = nd;
      pk[i] = ((u64)__float_as_uint(nd) << 32) | inv[i];
    }
#pragma unroll
    for (int st = 1; st < 16; st <<= 1)
#pragma unroll
      for (int i = 0; i < 16; i += 2*st)
        pk[i] = pk[i+st] > pk[i] ? pk[i+st] : pk[i];
    u64 best = pk[0];
    DPPMAX(0x111)  // row_shr:1
    DPPMAX(0x112)
    DPPMAX(0x114)
    DPPMAX(0x118)
    DPPMAX(0x142)  // row_bcast15
    DPPMAX(0x143)  // row_bcast31 -> lane 63 has wave max
    if (lane == 63) {
      slotP[s&1][w] = best;
      int bi3 = 3 * (int)(~(unsigned)best);
      slotC[s&1][w][0] = Xl[bi3];
      slotC[s&1][w][1] = Xl[bi3+1];
      slotC[s&1][w][2] = Xl[bi3+2];
    }
    __syncthreads();
    // packs + coords read concurrently; coords selected by cndmask
    const int par = s & 1;
    u64 s0 = slotP[par][0], s1 = slotP[par][1], s2 = slotP[par][2], s3 = slotP[par][3];
    f32x4 c0v = *(const f32x4*)&slotC[par][0][0];
    f32x4 c1v = *(const f32x4*)&slotC[par][1][0];
    f32x4 c2v = *(const f32x4*)&slotC[par][2][0];
    f32x4 c3v = *(const f32x4*)&slotC[par][3][0];
    u64 m = s0; f32x4 cw = c0v;
    if (s1 > m) { m = s1; cw = c1v; }
    if (s2 > m) { m = s2; cw = c2v; }
    if (s3 > m) { m = s3; cw = c3v; }
    cx = cw[0]; cy = cw[1]; cz = cw[2];
  }
  __syncthreads();
  float* o = newxyz + (size_t)b * NS * 3;
  for (int i = t; i < NS*3; i += 256) o[i] = cenL[i];
}

// ---------------------------------------------------------------- KNN
__global__ __launch_bounds__(64) void k_knn(const float* __restrict__ xyz,
                                            const float* __restrict__ newxyz,
                                            int* __restrict__ knn_idx,
                                            float* __restrict__ gnorm) {
  const int p = blockIdx.x;
  const int b = p >> 10;
  const int lane = threadIdx.x;
  const float* X = xyz + (size_t)b * NP * 3;
  __shared__ float d2[NP];
  float cx = newxyz[3*p], cy = newxyz[3*p+1], cz = newxyz[3*p+2];
  float sc = cx*cx + cy*cy + cz*cz;
#pragma unroll 4
  for (int i = 0; i < NP/64; ++i) {
    int n = lane + 64*i;
    float x = X[3*n], y = X[3*n+1], z = X[3*n+2];
    float sx = x*x + y*y + z*z;
    float dot = cx*x + cy*y + cz*z;
    d2[n] = sc + sx - 2.0f*dot;
  }
  for (int it = 0; it < NK; ++it) {
    float bv = 3.0e38f; int bi = 0x7fffffff;
#pragma unroll 8
    for (int i = 0; i < NP/64; ++i) {
      int n = lane + 64*i;
      float v = d2[n];
      if (v < bv) { bv = v; bi = n; }
    }
#pragma unroll
    for (int off = 32; off; off >>= 1) {
      float ov = __shfl_xor(bv, off);
      int   oi = __shfl_xor(bi, off);
      if (ov < bv || (ov == bv && oi < bi)) { bv = ov; bi = oi; }
    }
    if (lane == 0) {
      d2[bi] = 3.3e38f;
      knn_idx[p*NK + it] = bi;
      float* g = gnorm + ((size_t)p*NK + it)*3;
      g[0] = X[3*bi]   - cx;
      g[1] = X[3*bi+1] - cy;
      g[2] = X[3*bi+2] - cz;
    }
  }
}

// ---------------------------------------------------------------- MLP layer 1
__global__ __launch_bounds__(256) void k_layer1(const float* __restrict__ points,
                                                const int* __restrict__ knn_idx,
                                                const float* __restrict__ gnorm,
                                                const float* __restrict__ w1,
                                                float* __restrict__ y,
                                                float* __restrict__ stats) {
  const int r0 = blockIdx.x * 64;
  const int t = threadIdx.x;
  __shared__ float Xs[64][69];
  __shared__ float Ws[64][69];
  __shared__ int nid[64];
  __shared__ float ps[4][64], pss[4][64];
  if (t < 64) nid[t] = knn_idx[r0 + t];
  __syncthreads();
  for (int idx = t; idx < 64*67; idx += 256) {
    int r = idx / 67, c = idx % 67;
    int row = r0 + r;
    float v;
    if (c < 3) v = gnorm[(size_t)row*3 + c];
    else {
      int bb = row >> 15;
      int n = nid[r];
      v = points[((size_t)bb*NP + n)*NCIN + (c-3)];
    }
    Xs[r][c] = v;
  }
  for (int idx = t; idx < 64*67; idx += 256) {
    int o = idx / 67, c = idx % 67;
    Ws[o][c] = w1[idx];
  }
  __syncthreads();
  const int col = t & 63;
  const int rb  = t >> 6;
  float s1 = 0.f, s2 = 0.f;
  for (int i = 0; i < 16; ++i) {
    int r = rb + 4*i;
    float acc = 0.f;
#pragma unroll
    for (int c = 0; c < 67; ++c) acc += Xs[r][c] * Ws[col][c];
    y[(size_t)(r0 + r)*64 + col] = acc;
    s1 += acc; s2 += acc*acc;
  }
  ps[rb][col] = s1; pss[rb][col] = s2;
  __syncthreads();
  if (t < 64) {
    float a = ps[0][t]+ps[1][t]+ps[2][t]+ps[3][t];
    float q = pss[0][t]+pss[1][t]+pss[2][t]+pss[3][t];
    atomicAdd(&stats[t], a);
    atomicAdd(&stats[64 + t], q);
  }
}

// ---------------------------------------------------------------- MLP layers 2/3
template <int COUT>
__global__ __launch_bounds__(256) void k_layer(const float* __restrict__ xin,
                                               const float* __restrict__ aff,
                                               const float* __restrict__ w,
                                               float* __restrict__ y,
                                               float* __restrict__ stats) {
  const int r0 = blockIdx.x * 64;
  const int t = threadIdx.x;
  __shared__ float Xs[64][65];
  __shared__ float Ws[COUT][65];
  __shared__ float sa[64], sb[64];
  constexpr int NTR = 256 / COUT;
  __shared__ float ps[NTR][COUT], pss[NTR][COUT];
  if (t < 64) { sa[t] = aff[t]; sb[t] = aff[64 + t]; }
  __syncthreads();
  for (int idx = t; idx < 64*64; idx += 256) {
    int r = idx >> 6, c = idx & 63;
    float v = xin[(size_t)r0*64 + idx];
    Xs[r][c] = fmaxf(sa[c]*v + sb[c], 0.0f);
  }
  for (int idx = t; idx < COUT*64; idx += 256) {
    int o = idx >> 6, c = idx & 63;
    Ws[o][c] = w[idx];
  }
  __syncthreads();
  const int col = t & (COUT-1);
  const int rb  = t / COUT;
  float s1 = 0.f, s2 = 0.f;
  for (int i = 0; i < 64/NTR; ++i) {
    int r = rb + NTR*i;
    float acc = 0.f;
#pragma unroll
    for (int c = 0; c < 64; ++c) acc += Xs[r][c] * Ws[col][c];
    y[(size_t)(r0 + r)*COUT + col] = acc;
    s1 += acc; s2 += acc*acc;
  }
  ps[rb][col] = s1; pss[rb][col] = s2;
  __syncthreads();
  if (t < COUT) {
    float a = 0.f, q = 0.f;
    for (int n = 0; n < NTR; ++n) { a += ps[n][t]; q += pss[n][t]; }
    atomicAdd(&stats[t], a);
    atomicAdd(&stats[COUT + t], q);
  }
}

// ---------------------------------------------------------------- BN stats -> affine
__global__ void k_finalize(const float* __restrict__ stats, const float* __restrict__ g,
                           const float* __restrict__ b, float* __restrict__ aff, int cout) {
  int t = threadIdx.x;
  if (t < cout) {
    const float inv = 1.0f / (float)NM;
    float m = stats[t] * inv;
    float var = stats[cout + t] * inv - m*m;
    float a = g[t] * rsqrtf(var + EPSF);
    aff[t] = a;
    aff[cout + t] = b[t] - m * a;
  }
}

// ---------------------------------------------------------------- pack weights (bf16 B-fragment layout)
__global__ __launch_bounds__(256) void k_pack(const float* __restrict__ ws,
                                              const float* __restrict__ wqkv,
                                              const float* __restrict__ wo,
                                              ushort_t* __restrict__ wpk) {
  int gid = blockIdx.x*256 + threadIdx.x;    // < 294912
  const float* src; int N_; int rem;
  if (gid < 163840)      { int mat = gid >> 14; rem = gid & 16383; src = ws  + (size_t)mat*16384; N_ = 128; }
  else if (gid < 262144) { int g2 = gid - 163840; int d = g2/49152; rem = g2 - d*49152; src = wqkv + (size_t)d*49152; N_ = 384; }
  else                   { int g3 = gid - 262144; int d = g3 >> 14; rem = g3 & 16383;  src = wo  + (size_t)d*16384; N_ = 128; }
  int NTN = N_ >> 4;
  int tile = rem >> 9, r = rem & 511;
  int tk = tile / NTN, tn = tile % NTN;
  int lane2 = r >> 3, jj = r & 7;
  int k = tk*32 + (lane2 >> 4)*8 + jj;
  int n = tn*16 + (lane2 & 15);
  wpk[gid] = f2b(src[(size_t)k*N_ + n]);
}

// ---------------------------------------------------------------- fused per-group v4
// hcur fp32 lives in REGISTERS (MFMA C-frag layout: row=mi*16+hi4*4+r,
// col=32w+ci*16+lo16). LDS: hbS 8K + psisS 12.5K + scratch 27K = 47.5K
// -> 3 blocks/CU. LN/softmax reduced via DPP; rowStat (1K) one round trip.
__global__ __launch_bounds__(256, 3) void k_group(
    const float* __restrict__ h3, const float* __restrict__ aff3,
    const float* __restrict__ gnorm,
    const ushort_t* __restrict__ wpk,
    const float* __restrict__ wb, const float* __restrict__ alpha,
    const float* __restrict__ ln1g, const float* __restrict__ ln1b,
    const float* __restrict__ ln2g, const float* __restrict__ ln2b,
    float* __restrict__ out) {
  const int p = blockIdx.x;
  const int t = threadIdx.x;
  const int lane = t & 63;
  const int w = t >> 6;
  const int lo16 = lane & 15;
  const int hi4 = lane >> 4;

  __shared__ __align__(16) ushort_t hbS[NK*NC];        // 8K bf16 swizzled
  __shared__ __align__(16) ushort_t psisS[5*32*40];    // 12.5K
  __shared__ __align__(16) unsigned char scratch[27648];

  // psi views
  float*    ddAF = (float*)scratch;                 // [32][33]
  float*    pxF  = (float*)(scratch + 4224);        // 96
  float*    dinvF= (float*)(scratch + 4608);        // 32
  float*    sigF = (float*)(scratch + 4736);        // 8
  ushort_t* LbS  = (ushort_t*)(scratch + 4768);     // [32][40]
  ushort_t* PmS  = (ushort_t*)(scratch + 7328);     // 3x[32][40]
  // attention views
  ushort_t* qS   = (ushort_t*)scratch;              // [32][136]
  ushort_t* kS2  = (ushort_t*)(scratch + 8704);     // [32][136]
  ushort_t* vTS  = (ushort_t*)(scratch + 17408);    // [128][40]
  // LN stats (disjoint from HjS [0:20480))
  float*    rowStat = (float*)(scratch + 20480);    // [32][4][2]

  const int c0 = 32*w + lo16, c1 = c0 + 16;

  // ---- init: px, hbS staging, hc regs
  if (t < 96) pxF[t] = gnorm[(size_t)p*96 + t];
  const float* h3p = h3 + (size_t)p*4096;
#pragma unroll
  for (int i = 0; i < 16; ++i) {
    int idx = t + 256*i;
    int c = idx & 127, row = idx >> 7;
    float v = fmaxf(aff3[c]*h3p[idx] + aff3[128+c], 0.f);
    int ha = ((row << 8) + (c << 1)) ^ ((row & 7) << 4);
    hbS[ha >> 1] = f2b(v);
  }
  float hc[2][2][4];
  {
    float ga0 = aff3[c0], gb0 = aff3[128+c0];
    float ga1 = aff3[c1], gb1 = aff3[128+c1];
#pragma unroll
    for (int mi = 0; mi < 2; ++mi)
#pragma unroll
      for (int r = 0; r < 4; ++r) {
        int row = mi*16 + hi4*4 + r;
        hc[mi][0][r] = fmaxf(ga0*h3p[row*NC + c0] + gb0, 0.f);
        hc[mi][1][r] = fmaxf(ga1*h3p[row*NC + c1] + gb1, 0.f);
      }
  }
  __syncthreads();
  // ---- dd
  for (int i = t; i < 1024; i += 256) {
    int k = i >> 5, l = i & 31;
    float dx = pxF[k*3]  -pxF[l*3];
    float dy = pxF[k*3+1]-pxF[l*3+1];
    float dz = pxF[k*3+2]-pxF[l*3+2];
    ddAF[k*33+l] = dx*dx + dy*dy + dz*dz;
  }
  __syncthreads();
  float part = 0.f;
  for (int i = t; i < 1024; i += 256) part += sqrtf(ddAF[(i>>5)*33 + (i&31)] + 1e-12f);
#pragma unroll
  for (int off = 32; off; off >>= 1) part += __shfl_xor(part, off);
  if (lane == 0) sigF[w] = part;
  __syncthreads();
  if (t == 0) {
    float sg = (sigF[0]+sigF[1]+sigF[2]+sigF[3]) * (1.0f/1024.0f);
    sigF[4] = 2.0f*sg*sg + 1e-12f;
  }
  __syncthreads();
  const float denom = sigF[4];
  for (int i = t; i < 1024; i += 256) {
    int k = i >> 5, l = i & 31;
    ddAF[k*33+l] = expf(-ddAF[k*33+l] / denom);
  }
  __syncthreads();
  if (t < 32) {
    float s = 0.f;
    for (int l = 0; l < 32; ++l) s += ddAF[t*33 + l];
    dinvF[t] = rsqrtf(s + 1e-12f);
  }
  __syncthreads();
  for (int i = t; i < 1024; i += 256) {
    int k = i >> 5, l = i & 31;
    float v = -(dinvF[k] * ddAF[k*33+l] * dinvF[l]);
    if (k == l) v += 1.0f;
    LbS[k*40+l] = f2b(v);
  }
  __syncthreads();
  // L^2,L^3,L^4 via MFMA (B uses symmetry of L)
  {
    int mi2 = w >> 1, ni2 = w & 1;
    int arow = (mi2*16 + lo16)*80 + (hi4 << 4);
    int brow = (ni2*16 + lo16)*80 + (hi4 << 4);
    bf16x8 bfr = *(const bf16x8*)((const char*)LbS + brow);
#pragma unroll
    for (int m = 2; m <= 4; ++m) {
      const ushort_t* Asrc = (m == 2) ? LbS : (PmS + (m-3)*1280);
      bf16x8 afr = *(const bf16x8*)((const char*)Asrc + arow);
      f32x4 z = {0.f,0.f,0.f,0.f};
      f32x4 pv = MFMA(afr, bfr, z);
      int rb2 = mi2*16 + hi4*4;
      int cl = ni2*16 + lo16;
#pragma unroll
      for (int r = 0; r < 4; ++r) PmS[(m-2)*1280 + (rb2+r)*40 + cl] = f2b(pv[r]);
      __syncthreads();
    }
  }
  for (int i = t; i < 1024; i += 256) {
    int k = i >> 5, l = i & 31;
    float lb = b2f(LbS[k*40+l]);
    float p2 = b2f(PmS[k*40+l]);
    float p3 = b2f(PmS[1280 + k*40+l]);
    float p4 = b2f(PmS[2560 + k*40+l]);
    float diag = (k == l) ? 1.0f : 0.0f;
#pragma unroll
    for (int j = 0; j < NJ; ++j) {
      float sj = -0.05f * (float)(1 << j);
      float cc2 = 0.5f*sj*sj;
      float cc3 = cc2*sj*(1.0f/3.0f);
      float cc4 = cc3*sj*0.25f;
      psisS[j*1280 + k*40 + l] = f2b(diag + sj*lb + cc2*p2 + cc3*p3 + cc4*p4);
    }
  }

  // ---- depth loop
  for (int d = 0; d < NDEPTH; ++d) {
    // ===== mix: j pairs {0,1},{2,3},{4}
    f32x4 m00 = {0.f,0.f,0.f,0.f}, m01 = m00, m10 = m00, m11 = m00;
    for (int jp = 0; jp < 3; ++jp) {
      const int njp = (jp == 2) ? 1 : 2;
      __syncthreads();                       // HjS free / hbS writes done
      for (int jj = 0; jj < njp; ++jj) {
        int j = 2*jp + jj;
        ushort_t* HjS = (ushort_t*)scratch + jj*5120;  // [128][40]
        const ushort_t* Wp = wpk + (size_t)(d*NJ + j)*16384;
        const float alj = alpha[d*NJ + j];
#pragma unroll
        for (int tni = 0; tni < 2; ++tni) {
          int tn = 2*w + tni;
          f32x4 acc0 = {0.f,0.f,0.f,0.f}, acc1 = acc0;
#pragma unroll
          for (int tk = 0; tk < 4; ++tk) {
            bf16x8 bfr = *(const bf16x8*)(Wp + ((tk*8 + tn) << 9) + (lane << 3));
            int row0 = lo16;
            int ba0 = ((row0 << 8) + (tk << 6) + (hi4 << 4)) ^ ((row0 & 7) << 4);
            bf16x8 a0 = *(const bf16x8*)((const char*)hbS + ba0);
            acc0 = MFMA(a0, bfr, acc0);
            int row1 = 16 + lo16;
            int ba1 = ((row1 << 8) + (tk << 6) + (hi4 << 4)) ^ ((row1 & 7) << 4);
            bf16x8 a1 = *(const bf16x8*)((const char*)hbS + ba1);
            acc1 = MFMA(a1, bfr, acc1);
          }
          int c = tn*16 + lo16;
          int rbase = hi4*4;
#pragma unroll
          for (int r = 0; r < 4; ++r) {
            HjS[c*40 + rbase + r]      = f2b(alj * acc0[r]);
            HjS[c*40 + 16 + rbase + r] = f2b(alj * acc1[r]);
          }
        }
      }
      __syncthreads();
      for (int jj = 0; jj < njp; ++jj) {
        int j = 2*jp + jj;
        const char* psj = (const char*)(psisS + j*1280);
        const char* HjB = (const char*)scratch + jj*10240;
        int koff = hi4 << 4;
        bf16x8 pa0 = *(const bf16x8*)(psj + lo16*80 + koff);
        bf16x8 pa1 = *(const bf16x8*)(psj + (16 + lo16)*80 + koff);
        bf16x8 hb0 = *(const bf16x8*)(HjB + c0*80 + koff);
        bf16x8 hb1 = *(const bf16x8*)(HjB + c1*80 + koff);
        m00 = MFMA(pa0, hb0, m00);
        m01 = MFMA(pa0, hb1, m01);
        m10 = MFMA(pa1, hb0, m10);
        m11 = MFMA(pa1, hb1, m11);
      }
    }
    // ===== u = hc + relu(mix+wb) in regs; LN1 via DPP + rowStat
    float u[2][2][4];
    {
      float wb0 = wb[d*NC + c0], wb1 = wb[d*NC + c1];
#pragma unroll
      for (int r = 0; r < 4; ++r) {
        u[0][0][r] = hc[0][0][r] + fmaxf(m00[r] + wb0, 0.f);
        u[0][1][r] = hc[0][1][r] + fmaxf(m01[r] + wb1, 0.f);
        u[1][0][r] = hc[1][0][r] + fmaxf(m10[r] + wb0, 0.f);
        u[1][1][r] = hc[1][1][r] + fmaxf(m11[r] + wb1, 0.f);
      }
#pragma unroll
      for (int mi = 0; mi < 2; ++mi)
#pragma unroll
        for (int r = 0; r < 4; ++r) {
          float s = u[mi][0][r] + u[mi][1][r];
          float q = u[mi][0][r]*u[mi][0][r] + u[mi][1][r]*u[mi][1][r];
          s = dpp_sum16(s);
          q = dpp_sum16(q);
          if (lo16 == 0) {
            int row = mi*16 + hi4*4 + r;
            rowStat[row*8 + w*2]     = s;
            rowStat[row*8 + w*2 + 1] = q;
          }
        }
    }
    __syncthreads();   // (A) rowStat visible; all waves past mix
    {
      float g0 = ln1g[d*NC + c0], b0 = ln1b[d*NC + c0];
      float g1 = ln1g[d*NC + c1], b1 = ln1b[d*NC + c1];
#pragma unroll
      for (int mi = 0; mi < 2; ++mi)
#pragma unroll
        for (int r = 0; r < 4; ++r) {
          int row = mi*16 + hi4*4 + r;
          f32x4 a = *(const f32x4*)(rowStat + row*8);
          f32x4 bq = *(const f32x4*)(rowStat + row*8 + 4);
          float mu = (a[0]+a[2]+bq[0]+bq[2]) * (1.0f/128.0f);
          float ex2 = (a[1]+a[3]+bq[1]+bq[3]) * (1.0f/128.0f);
          float rs = rsqrtf(ex2 - mu*mu + EPSF);
          float h0 = (u[mi][0][r] - mu)*rs*g0 + b0;
          float h1 = (u[mi][1][r] - mu)*rs*g1 + b1;
          hc[mi][0][r] = h0; hc[mi][1][r] = h1;
          int ha0 = ((row << 8) + (c0 << 1)) ^ ((row & 7) << 4);
          int ha1 = ((row << 8) + (c1 << 1)) ^ ((row & 7) << 4);
          hbS[ha0 >> 1] = f2b(h0);
          hbS[ha1 >> 1] = f2b(h1);
        }
    }
    __syncthreads();   // (B) hbS(LN1) ready, scratch free
    // ===== qkv: 48 tiles, 12/wave
    const ushort_t* Wq = wpk + 163840 + (size_t)d*49152;
#pragma unroll
    for (int ti = 0; ti < 12; ++ti) {
      int tile = w + 4*ti;
      int mi = (tile >= 24) ? 1 : 0;
      int tn = tile - 24*mi;
      int comp = tn >> 3;
      int cb = (tn & 7) * 16;
      f32x4 acc = {0.f,0.f,0.f,0.f};
#pragma unroll
      for (int tk = 0; tk < 4; ++tk) {
        bf16x8 bfr = *(const bf16x8*)(Wq + ((tk*24 + tn) << 9) + (lane << 3));
        int row = mi*16 + lo16;
        int ba = ((row << 8) + (tk << 6) + (hi4 << 4)) ^ ((row & 7) << 4);
        bf16x8 a = *(const bf16x8*)((const char*)hbS + ba);
        acc = MFMA(a, bfr, acc);
      }
      int cl = cb + lo16;
      int rb2 = mi*16 + hi4*4;
      if (comp == 0) {
#pragma unroll
        for (int r = 0; r < 4; ++r) qS[(rb2+r)*136 + cl] = f2b(acc[r]);
      } else if (comp == 1) {
#pragma unroll
        for (int r = 0; r < 4; ++r) kS2[(rb2+r)*136 + cl] = f2b(acc[r]);
      } else {
#pragma unroll
        for (int r = 0; r < 4; ++r) vTS[cl*40 + rb2 + r] = f2b(acc[r]);
      }
    }
    __syncthreads();
    // ===== scores into regs: wave w -> pairs (h,mi) = pi>>1,pi&1 for pi=w,w+4
    float scr[2][2][4];
#pragma unroll
    for (int ti = 0; ti < 2; ++ti) {
      int pi = w + 4*ti;
      int h = pi >> 1, mi = pi & 1;
      int koff = h*64 + (hi4 << 4);
      bf16x8 qa = *(const bf16x8*)((const char*)qS + (mi*16 + lo16)*272 + koff);
#pragma unroll
      for (int ni = 0; ni < 2; ++ni) {
        bf16x8 kb = *(const bf16x8*)((const char*)kS2 + (ni*16 + lo16)*272 + koff);
        f32x4 z = {0.f,0.f,0.f,0.f};
        f32x4 sv = MFMA(qa, kb, z);
#pragma unroll
        for (int r = 0; r < 4; ++r) scr[ti][ni][r] = sv[r] * 0.17677669529663687f;
      }
    }
    __syncthreads();   // q consumed; att may overwrite qS
    // ===== softmax in regs (DPP row reduce), att -> qS
#pragma unroll
    for (int ti = 0; ti < 2; ++ti) {
      int pi = w + 4*ti;
      int h = pi >> 1, mi = pi & 1;
#pragma unroll
      for (int r = 0; r < 4; ++r) {
        float s0 = scr[ti][0][r], s1 = scr[ti][1][r];
        float mx = dpp_max16(fmaxf(s0, s1));
        float e0 = expf(s0 - mx), e1 = expf(s1 - mx);
        float sum = dpp_sum16(e0 + e1);
        float iv = 1.0f / sum;
        int row = mi*16 + hi4*4 + r;
        qS[row*136 + h*32 + lo16]      = f2b(e0*iv);
        qS[row*136 + h*32 + 16 + lo16] = f2b(e1*iv);
      }
    }
    __syncthreads();
    // ===== PV -> hbS (o, bf16 swizzled)
#pragma unroll
    for (int ti = 0; ti < 4; ++ti) {
      int tile = w + 4*ti;
      int h = tile >> 2, mi = (tile >> 1) & 1, ni = tile & 1;
      bf16x8 aa = *(const bf16x8*)((const char*)qS + (mi*16 + lo16)*272 + h*64 + (hi4 << 4));
      bf16x8 vb = *(const bf16x8*)((const char*)vTS + (h*32 + ni*16 + lo16)*80 + (hi4 << 4));
      f32x4 z = {0.f,0.f,0.f,0.f};
      f32x4 ov = MFMA(aa, vb, z);
      int col = h*32 + ni*16 + lo16;
      int rb2 = mi*16 + hi4*4;
#pragma unroll
      for (int r = 0; r < 4; ++r) {
        int row = rb2 + r;
        int ha = ((row << 8) + (col << 1)) ^ ((row & 7) << 4);
        hbS[ha >> 1] = f2b(ov[r]);
      }
    }
    __syncthreads();
    // ===== proj + residual in regs; LN2 via DPP + rowStat
    const ushort_t* Wop = wpk + 262144 + (size_t)d*16384;
#pragma unroll
    for (int tni = 0; tni < 2; ++tni) {
      int tn = 2*w + tni;
      f32x4 acc0 = {0.f,0.f,0.f,0.f}, acc1 = acc0;
#pragma unroll
      for (int tk = 0; tk < 4; ++tk) {
        bf16x8 bfr = *(const bf16x8*)(Wop + ((tk*8 + tn) << 9) + (lane << 3));
        int row0 = lo16;
        int ba0 = ((row0 << 8) + (tk << 6) + (hi4 << 4)) ^ ((row0 & 7) << 4);
        bf16x8 a0 = *(const bf16x8*)((const char*)hbS + ba0);
        acc0 = MFMA(a0, bfr, acc0);
        int row1 = 16 + lo16;
        int ba1 = ((row1 << 8) + (tk << 6) + (hi4 << 4)) ^ ((row1 & 7) << 4);
        bf16x8 a1 = *(const bf16x8*)((const char*)hbS + ba1);
        acc1 = MFMA(a1, bfr, acc1);
      }
#pragma unroll
      for (int r = 0; r < 4; ++r) {
        u[0][tni][r] = hc[0][tni][r] + acc0[r];
        u[1][tni][r] = hc[1][tni][r] + acc1[r];
      }
    }
#pragma unroll
    for (int mi = 0; mi < 2; ++mi)
#pragma unroll
      for (int r = 0; r < 4; ++r) {
        float s = u[mi][0][r] + u[mi][1][r];
        float q = u[mi][0][r]*u[mi][0][r] + u[mi][1][r]*u[mi][1][r];
        s = dpp_sum16(s);
        q = dpp_sum16(q);
        if (lo16 == 0) {
          int row = mi*16 + hi4*4 + r;
          rowStat[row*8 + w*2]     = s;   // vTS dead (all waves past PV barrier)
          rowStat[row*8 + w*2 + 1] = q;
        }
      }
    __syncthreads();   // (C)
    {
      float g0 = ln2g[d*NC + c0], b0 = ln2b[d*NC + c0];
      float g1 = ln2g[d*NC + c1], b1 = ln2b[d*NC + c1];
#pragma unroll
      for (int mi = 0; mi < 2; ++mi)
#pragma unroll
        for (int r = 0; r < 4; ++r) {
          int row = mi*16 + hi4*4 + r;
          f32x4 a = *(const f32x4*)(rowStat + row*8);
          f32x4 bq = *(const f32x4*)(rowStat + row*8 + 4);
          float mu = (a[0]+a[2]+bq[0]+bq[2]) * (1.0f/128.0f);
          float ex2 = (a[1]+a[3]+bq[1]+bq[3]) * (1.0f/128.0f);
          float rs = rsqrtf(ex2 - mu*mu + EPSF);
          float h0 = (u[mi][0][r] - mu)*rs*g0 + b0;
          float h1 = (u[mi][1][r] - mu)*rs*g1 + b1;
          hc[mi][0][r] = h0; hc[mi][1][r] = h1;
          int ha0 = ((row << 8) + (c0 << 1)) ^ ((row & 7) << 4);
          int ha1 = ((row << 8) + (c1 << 1)) ^ ((row & 7) << 4);
          hbS[ha0 >> 1] = f2b(h0);
          hbS[ha1 >> 1] = f2b(h1);
        }
    }
    // next depth's jp-loop barrier (or reg-only maxpool) provides the guard
  }
  // ---- maxpool over K (regs + 2 shfl)
  {
    float v0 = hc[0][0][0], v1 = hc[0][1][0];
#pragma unroll
    for (int r = 1; r < 4; ++r) { v0 = fmaxf(v0, hc[0][0][r]); v1 = fmaxf(v1, hc[0][1][r]); }
#pragma unroll
    for (int r = 0; r < 4; ++r) { v0 = fmaxf(v0, hc[1][0][r]); v1 = fmaxf(v1, hc[1][1][r]); }
    v0 = fmaxf(v0, __shfl_xor(v0, 16)); v0 = fmaxf(v0, __shfl_xor(v0, 32));
    v1 = fmaxf(v1, __shfl_xor(v1, 16)); v1 = fmaxf(v1, __shfl_xor(v1, 32));
    if (hi4 == 0) {
      out[(size_t)p*NC + c0] = v0;
      out[(size_t)p*NC + c1] = v1;
    }
  }
}

// ---------------------------------------------------------------- launcher
extern "C" void kernel_launch(void* const* d_in, const int* in_sizes, int n_in,
                              void* d_out, int out_size, void* d_ws, size_t ws_size,
                              hipStream_t stream) {
  const float* xyz    = (const float*)d_in[0];
  const float* points = (const float*)d_in[1];
  const float* w1     = (const float*)d_in[2];
  const float* g1     = (const float*)d_in[3];
  const float* b1     = (const float*)d_in[4];
  const float* w2     = (const float*)d_in[5];
  const float* g2     = (const float*)d_in[6];
  const float* b2     = (const float*)d_in[7];
  const float* w3     = (const float*)d_in[8];
  const float* g3     = (const float*)d_in[9];
  const float* b3     = (const float*)d_in[10];
  const float* wsW    = (const float*)d_in[11];
  const float* wb     = (const float*)d_in[12];
  const float* alpha  = (const float*)d_in[13];
  const float* wqkv   = (const float*)d_in[14];
  const float* wo     = (const float*)d_in[15];
  const float* ln1g   = (const float*)d_in[16];
  const float* ln1b   = (const float*)d_in[17];
  const float* ln2g   = (const float*)d_in[18];
  const float* ln2b   = (const float*)d_in[19];
  float* outp = (float*)d_out;

  float* wsf   = (float*)d_ws;
  float* gnorm = wsf;                        // 786432 f
  float* stats = wsf + 786432;               // 768 f
  float* aff   = wsf + 787200;               // 768 f
  int*   knn   = (int*)(wsf + 787968);       // 262144 i  (reused as wpk after k_layer1)
  ushort_t* wpk = (ushort_t*)(wsf + 787968); // 294912 bf16
  float* h2    = wsf + 1050112;              // 16777216 f
  float* hX    = wsf + 17827328;             // 33554432 f

  hipMemsetAsync(stats, 0, 768*sizeof(float), stream);
  k_fps<<<NB, 256, 0, stream>>>(xyz, outp);
  k_knn<<<NPTS, 64, 0, stream>>>(xyz, outp, knn, gnorm);
  k_layer1<<<NM/64, 256, 0, stream>>>(points, knn, gnorm, w1, hX, stats);
  k_pack<<<294912/256, 256, 0, stream>>>(wsW, wqkv, wo, wpk);
  k_finalize<<<1, 128, 0, stream>>>(stats, g1, b1, aff, 64);
  k_layer<64><<<NM/64, 256, 0, stream>>>(hX, aff, w2, h2, stats + 256);
  k_finalize<<<1, 128, 0, stream>>>(stats + 256, g2, b2, aff + 256, 64);
  k_layer<128><<<NM/64, 256, 0, stream>>>(h2, aff + 256, w3, hX, stats + 512);
  k_finalize<<<1, 128, 0, stream>>>(stats + 512, g3, b3, aff + 512, 128);
  k_group<<<NPTS, 256, 0, stream>>>(hX, aff + 512, gnorm, wpk, wb, alpha,
                                    ln1g, ln1b, ln2g, ln2b, outp + (size_t)NB*NS*3);
}

// Round 8
// 2076.881 us; speedup vs baseline: 1.0208x; 1.0208x over previous
//
#include <hip/hip_runtime.h>
#include <math.h>

#define NB 8
#define NP 4096
#define NCIN 64
#define NS 1024
#define NK 32
#define NC 128
#define NJ 5
#define NDEPTH 2
#define NH 4
#define NPTS (NB*NS)       /* 8192 groups */
#define NM (NPTS*NK)       /* 262144 rows */
#define EPSF 1e-5f

typedef float f32x4 __attribute__((ext_vector_type(4)));
typedef short bf16x8 __attribute__((ext_vector_type(8)));
typedef unsigned short ushort_t;
typedef unsigned long long u64;

#define MFMA(a,b,c) __builtin_amdgcn_mfma_f32_16x16x32_bf16(a,b,c,0,0,0)

__device__ __forceinline__ ushort_t f2b(float f) {
  unsigned int u = __float_as_uint(f);
  u = (u + 0x7fffu + ((u >> 16) & 1u)) >> 16;
  return (ushort_t)u;
}
__device__ __forceinline__ float b2f(ushort_t h) {
  unsigned int u = ((unsigned int)h) << 16;
  return __uint_as_float(u);
}

// DPP in-row-of-16 reduce (VALU pipe).
template<int CTRL>
__device__ __forceinline__ float dpp_f(float v) {
  return __int_as_float(__builtin_amdgcn_update_dpp(0, __float_as_int(v), CTRL, 0xf, 0xf, true));
}
__device__ __forceinline__ float dpp_sum16(float v) {
  v += dpp_f<0xB1>(v); v += dpp_f<0x4E>(v);
  v += dpp_f<0x141>(v); v += dpp_f<0x140>(v);
  return v;
}
__device__ __forceinline__ float dpp_max16(float v) {
  v = fmaxf(v, dpp_f<0xB1>(v)); v = fmaxf(v, dpp_f<0x4E>(v));
  v = fmaxf(v, dpp_f<0x141>(v)); v = fmaxf(v, dpp_f<0x140>(v));
  return v;
}

// ---------------------------------------------------------------- FPS
// 1024 threads, 4 pts/lane. DPP wave max; 16-slot LDS tree; no global
// stores in the loop (centroids staged in LDS).
#define DPPMAX(CTRL) { \
  unsigned lo2 = (unsigned)__builtin_amdgcn_update_dpp(0, (int)(unsigned)best, CTRL, 0xf, 0xf, true); \
  unsigned hi2 = (unsigned)__builtin_amdgcn_update_dpp(0, (int)(unsigned)(best >> 32), CTRL, 0xf, 0xf, true); \
  u64 o = ((u64)hi2 << 32) | lo2; \
  if (o > best) best = o; }

__global__ __launch_bounds__(1024) void k_fps(const float* __restrict__ xyz,
                                              float* __restrict__ newxyz) {
  const int b = blockIdx.x;
  const int t = threadIdx.x;
  const int lane = t & 63;
  const int w = t >> 6;              // 0..15
  __shared__ float Xl[NP*3];
  __shared__ float cenL[NS*3];
  __shared__ u64 slotP[2][16];
  const float* X = xyz + (size_t)b * NP * 3;
  for (int i = t; i < NP*3; i += 1024) Xl[i] = X[i];
  __syncthreads();
  float px[4], py[4], pz[4], dist[4];
  unsigned inv[4];
#pragma unroll
  for (int i = 0; i < 4; ++i) {
    int n = t + 1024*i;
    px[i] = Xl[3*n]; py[i] = Xl[3*n+1]; pz[i] = Xl[3*n+2];
    dist[i] = 1e10f;
    inv[i] = ~(unsigned)n;
  }
  float cx = Xl[0], cy = Xl[1], cz = Xl[2];   // far = 0 initially
  for (int s = 0; s < NS; ++s) {
    if (t == 0) { cenL[3*s] = cx; cenL[3*s+1] = cy; cenL[3*s+2] = cz; }
    u64 pk[4];
#pragma unroll
    for (int i = 0; i < 4; ++i) {
      float dx = px[i]-cx, dy = py[i]-cy, dz = pz[i]-cz;
      float d = fmaf(dx,dx, fmaf(dy,dy, dz*dz));
      float nd = fminf(dist[i], d);
      dist[i] = nd;
      pk[i] = ((u64)__float_as_uint(nd) << 32) | inv[i];
    }
    pk[0] = pk[1] > pk[0] ? pk[1] : pk[0];
    pk[2] = pk[3] > pk[2] ? pk[3] : pk[2];
    u64 best = pk[2] > pk[0] ? pk[2] : pk[0];
    DPPMAX(0x111)  // row_shr:1
    DPPMAX(0x112)
    DPPMAX(0x114)
    DPPMAX(0x118)
    DPPMAX(0x142)  // row_bcast15
    DPPMAX(0x143)  // row_bcast31 -> lane 63 has wave max
    if (lane == 63) slotP[s&1][w] = best;
    __syncthreads();
    const u64* sl = slotP[s&1];
    u64 v[16];
#pragma unroll
    for (int i = 0; i < 16; ++i) v[i] = sl[i];
#pragma unroll
    for (int st = 1; st < 16; st <<= 1)
#pragma unroll
      for (int i = 0; i < 16; i += 2*st)
        v[i] = v[i+st] > v[i] ? v[i+st] : v[i];
    int far = (int)(~(unsigned)v[0]);
    cx = Xl[3*far]; cy = Xl[3*far+1]; cz = Xl[3*far+2];
  }
  __syncthreads();
  float* o = newxyz + (size_t)b * NS * 3;
  for (int i = t; i < NS*3; i += 1024) o[i] = cenL[i];
}

// ---------------------------------------------------------------- KNN
__global__ __launch_bounds__(64) void k_knn(const float* __restrict__ xyz,
                                            const float* __restrict__ newxyz,
                                            int* __restrict__ knn_idx,
                                            float* __restrict__ gnorm) {
  const int p = blockIdx.x;
  const int b = p >> 10;
  const int lane = threadIdx.x;
  const float* X = xyz + (size_t)b * NP * 3;
  __shared__ float d2[NP];
  float cx = newxyz[3*p], cy = newxyz[3*p+1], cz = newxyz[3*p+2];
  float sc = cx*cx + cy*cy + cz*cz;
#pragma unroll 4
  for (int i = 0; i < NP/64; ++i) {
    int n = lane + 64*i;
    float x = X[3*n], y = X[3*n+1], z = X[3*n+2];
    float sx = x*x + y*y + z*z;
    float dot = cx*x + cy*y + cz*z;
    d2[n] = sc + sx - 2.0f*dot;
  }
  for (int it = 0; it < NK; ++it) {
    float bv = 3.0e38f; int bi = 0x7fffffff;
#pragma unroll 8
    for (int i = 0; i < NP/64; ++i) {
      int n = lane + 64*i;
      float v = d2[n];
      if (v < bv) { bv = v; bi = n; }
    }
#pragma unroll
    for (int off = 32; off; off >>= 1) {
      float ov = __shfl_xor(bv, off);
      int   oi = __shfl_xor(bi, off);
      if (ov < bv || (ov == bv && oi < bi)) { bv = ov; bi = oi; }
    }
    if (lane == 0) {
      d2[bi] = 3.3e38f;
      knn_idx[p*NK + it] = bi;
      float* g = gnorm + ((size_t)p*NK + it)*3;
      g[0] = X[3*bi]   - cx;
      g[1] = X[3*bi+1] - cy;
      g[2] = X[3*bi+2] - cz;
    }
  }
}

// ---------------------------------------------------------------- MLP layer 1
__global__ __launch_bounds__(256) void k_layer1(const float* __restrict__ points,
                                                const int* __restrict__ knn_idx,
                                                const float* __restrict__ gnorm,
                                                const float* __restrict__ w1,
                                                float* __restrict__ y,
                                                float* __restrict__ stats) {
  const int r0 = blockIdx.x * 64;
  const int t = threadIdx.x;
  __shared__ float Xs[64][69];
  __shared__ float Ws[64][69];
  __shared__ int nid[64];
  __shared__ float ps[4][64], pss[4][64];
  if (t < 64) nid[t] = knn_idx[r0 + t];
  __syncthreads();
  for (int idx = t; idx < 64*67; idx += 256) {
    int r = idx / 67, c = idx % 67;
    int row = r0 + r;
    float v;
    if (c < 3) v = gnorm[(size_t)row*3 + c];
    else {
      int bb = row >> 15;
      int n = nid[r];
      v = points[((size_t)bb*NP + n)*NCIN + (c-3)];
    }
    Xs[r][c] = v;
  }
  for (int idx = t; idx < 64*67; idx += 256) {
    int o = idx / 67, c = idx % 67;
    Ws[o][c] = w1[idx];
  }
  __syncthreads();
  const int col = t & 63;
  const int rb  = t >> 6;
  float s1 = 0.f, s2 = 0.f;
  for (int i = 0; i < 16; ++i) {
    int r = rb + 4*i;
    float acc = 0.f;
#pragma unroll
    for (int c = 0; c < 67; ++c) acc += Xs[r][c] * Ws[col][c];
    y[(size_t)(r0 + r)*64 + col] = acc;
    s1 += acc; s2 += acc*acc;
  }
  ps[rb][col] = s1; pss[rb][col] = s2;
  __syncthreads();
  if (t < 64) {
    float a = ps[0][t]+ps[1][t]+ps[2][t]+ps[3][t];
    float q = pss[0][t]+pss[1][t]+pss[2][t]+pss[3][t];
    atomicAdd(&stats[t], a);
    atomicAdd(&stats[64 + t], q);
  }
}

// ---------------------------------------------------------------- MLP layers 2/3
template <int COUT>
__global__ __launch_bounds__(256) void k_layer(const float* __restrict__ xin,
                                               const float* __restrict__ aff,
                                               const float* __restrict__ w,
                                               float* __restrict__ y,
                                               float* __restrict__ stats) {
  const int r0 = blockIdx.x * 64;
  const int t = threadIdx.x;
  __shared__ float Xs[64][65];
  __shared__ float Ws[COUT][65];
  __shared__ float sa[64], sb[64];
  constexpr int NTR = 256 / COUT;
  __shared__ float ps[NTR][COUT], pss[NTR][COUT];
  if (t < 64) { sa[t] = aff[t]; sb[t] = aff[64 + t]; }
  __syncthreads();
  for (int idx = t; idx < 64*64; idx += 256) {
    int r = idx >> 6, c = idx & 63;
    float v = xin[(size_t)r0*64 + idx];
    Xs[r][c] = fmaxf(sa[c]*v + sb[c], 0.0f);
  }
  for (int idx = t; idx < COUT*64; idx += 256) {
    int o = idx >> 6, c = idx & 63;
    Ws[o][c] = w[idx];
  }
  __syncthreads();
  const int col = t & (COUT-1);
  const int rb  = t / COUT;
  float s1 = 0.f, s2 = 0.f;
  for (int i = 0; i < 64/NTR; ++i) {
    int r = rb + NTR*i;
    float acc = 0.f;
#pragma unroll
    for (int c = 0; c < 64; ++c) acc += Xs[r][c] * Ws[col][c];
    y[(size_t)(r0 + r)*COUT + col] = acc;
    s1 += acc; s2 += acc*acc;
  }
  ps[rb][col] = s1; pss[rb][col] = s2;
  __syncthreads();
  if (t < COUT) {
    float a = 0.f, q = 0.f;
    for (int n = 0; n < NTR; ++n) { a += ps[n][t]; q += pss[n][t]; }
    atomicAdd(&stats[t], a);
    atomicAdd(&stats[COUT + t], q);
  }
}

// ---------------------------------------------------------------- BN stats -> affine
__global__ void k_finalize(const float* __restrict__ stats, const float* __restrict__ g,
                           const float* __restrict__ b, float* __restrict__ aff, int cout) {
  int t = threadIdx.x;
  if (t < cout) {
    const float inv = 1.0f / (float)NM;
    float m = stats[t] * inv;
    float var = stats[cout + t] * inv - m*m;
    float a = g[t] * rsqrtf(var + EPSF);
    aff[t] = a;
    aff[cout + t] = b[t] - m * a;
  }
}

// ---------------------------------------------------------------- pack weights (bf16 B-fragment layout)
__global__ __launch_bounds__(256) void k_pack(const float* __restrict__ ws,
                                              const float* __restrict__ wqkv,
                                              const float* __restrict__ wo,
                                              ushort_t* __restrict__ wpk) {
  int gid = blockIdx.x*256 + threadIdx.x;    // < 294912
  const float* src; int N_; int rem;
  if (gid < 163840)      { int mat = gid >> 14; rem = gid & 16383; src = ws  + (size_t)mat*16384; N_ = 128; }
  else if (gid < 262144) { int g2 = gid - 163840; int d = g2/49152; rem = g2 - d*49152; src = wqkv + (size_t)d*49152; N_ = 384; }
  else                   { int g3 = gid - 262144; int d = g3 >> 14; rem = g3 & 16383;  src = wo  + (size_t)d*16384; N_ = 128; }
  int NTN = N_ >> 4;
  int tile = rem >> 9, r = rem & 511;
  int tk = tile / NTN, tn = tile % NTN;
  int lane2 = r >> 3, jj = r & 7;
  int k = tk*32 + (lane2 >> 4)*8 + jj;
  int n = tn*16 + (lane2 & 15);
  wpk[gid] = f2b(src[(size_t)k*N_ + n]);
}

// ---------------------------------------------------------------- fused per-group v4b
// Same as v4 but __launch_bounds__(256,2): unified VGPR+AGPR cap 256 ->
// no scratch spill (r7: cap 170 spilled hc/u/scr = 422 MB HBM writes).
__global__ __launch_bounds__(256, 2) void k_group(
    const float* __restrict__ h3, const float* __restrict__ aff3,
    const float* __restrict__ gnorm,
    const ushort_t* __restrict__ wpk,
    const float* __restrict__ wb, const float* __restrict__ alpha,
    const float* __restrict__ ln1g, const float* __restrict__ ln1b,
    const float* __restrict__ ln2g, const float* __restrict__ ln2b,
    float* __restrict__ out) {
  const int p = blockIdx.x;
  const int t = threadIdx.x;
  const int lane = t & 63;
  const int w = t >> 6;
  const int lo16 = lane & 15;
  const int hi4 = lane >> 4;

  __shared__ __align__(16) ushort_t hbS[NK*NC];        // 8K bf16 swizzled
  __shared__ __align__(16) ushort_t psisS[5*32*40];    // 12.5K
  __shared__ __align__(16) unsigned char scratch[27648];

  // psi views
  float*    ddAF = (float*)scratch;                 // [32][33]
  float*    pxF  = (float*)(scratch + 4224);        // 96
  float*    dinvF= (float*)(scratch + 4608);        // 32
  float*    sigF = (float*)(scratch + 4736);        // 8
  ushort_t* LbS  = (ushort_t*)(scratch + 4768);     // [32][40]
  ushort_t* PmS  = (ushort_t*)(scratch + 7328);     // 3x[32][40]
  // attention views
  ushort_t* qS   = (ushort_t*)scratch;              // [32][136]
  ushort_t* kS2  = (ushort_t*)(scratch + 8704);     // [32][136]
  ushort_t* vTS  = (ushort_t*)(scratch + 17408);    // [128][40]
  // LN stats (disjoint from HjS [0:20480))
  float*    rowStat = (float*)(scratch + 20480);    // [32][4][2]

  const int c0 = 32*w + lo16, c1 = c0 + 16;

  // ---- init: px, hbS staging, hc regs
  if (t < 96) pxF[t] = gnorm[(size_t)p*96 + t];
  const float* h3p = h3 + (size_t)p*4096;
#pragma unroll
  for (int i = 0; i < 16; ++i) {
    int idx = t + 256*i;
    int c = idx & 127, row = idx >> 7;
    float v = fmaxf(aff3[c]*h3p[idx] + aff3[128+c], 0.f);
    int ha = ((row << 8) + (c << 1)) ^ ((row & 7) << 4);
    hbS[ha >> 1] = f2b(v);
  }
  float hc[2][2][4];
  {
    float ga0 = aff3[c0], gb0 = aff3[128+c0];
    float ga1 = aff3[c1], gb1 = aff3[128+c1];
#pragma unroll
    for (int mi = 0; mi < 2; ++mi)
#pragma unroll
      for (int r = 0; r < 4; ++r) {
        int row = mi*16 + hi4*4 + r;
        hc[mi][0][r] = fmaxf(ga0*h3p[row*NC + c0] + gb0, 0.f);
        hc[mi][1][r] = fmaxf(ga1*h3p[row*NC + c1] + gb1, 0.f);
      }
  }
  __syncthreads();
  // ---- dd
  for (int i = t; i < 1024; i += 256) {
    int k = i >> 5, l = i & 31;
    float dx = pxF[k*3]  -pxF[l*3];
    float dy = pxF[k*3+1]-pxF[l*3+1];
    float dz = pxF[k*3+2]-pxF[l*3+2];
    ddAF[k*33+l] = dx*dx + dy*dy + dz*dz;
  }
  __syncthreads();
  float part = 0.f;
  for (int i = t; i < 1024; i += 256) part += sqrtf(ddAF[(i>>5)*33 + (i&31)] + 1e-12f);
#pragma unroll
  for (int off = 32; off; off >>= 1) part += __shfl_xor(part, off);
  if (lane == 0) sigF[w] = part;
  __syncthreads();
  if (t == 0) {
    float sg = (sigF[0]+sigF[1]+sigF[2]+sigF[3]) * (1.0f/1024.0f);
    sigF[4] = 2.0f*sg*sg + 1e-12f;
  }
  __syncthreads();
  const float denom = sigF[4];
  for (int i = t; i < 1024; i += 256) {
    int k = i >> 5, l = i & 31;
    ddAF[k*33+l] = expf(-ddAF[k*33+l] / denom);
  }
  __syncthreads();
  if (t < 32) {
    float s = 0.f;
    for (int l = 0; l < 32; ++l) s += ddAF[t*33 + l];
    dinvF[t] = rsqrtf(s + 1e-12f);
  }
  __syncthreads();
  for (int i = t; i < 1024; i += 256) {
    int k = i >> 5, l = i & 31;
    float v = -(dinvF[k] * ddAF[k*33+l] * dinvF[l]);
    if (k == l) v += 1.0f;
    LbS[k*40+l] = f2b(v);
  }
  __syncthreads();
  // L^2,L^3,L^4 via MFMA (B uses symmetry of L)
  {
    int mi2 = w >> 1, ni2 = w & 1;
    int arow = (mi2*16 + lo16)*80 + (hi4 << 4);
    int brow = (ni2*16 + lo16)*80 + (hi4 << 4);
    bf16x8 bfr = *(const bf16x8*)((const char*)LbS + brow);
#pragma unroll
    for (int m = 2; m <= 4; ++m) {
      const ushort_t* Asrc = (m == 2) ? LbS : (PmS + (m-3)*1280);
      bf16x8 afr = *(const bf16x8*)((const char*)Asrc + arow);
      f32x4 z = {0.f,0.f,0.f,0.f};
      f32x4 pv = MFMA(afr, bfr, z);
      int rb2 = mi2*16 + hi4*4;
      int cl = ni2*16 + lo16;
#pragma unroll
      for (int r = 0; r < 4; ++r) PmS[(m-2)*1280 + (rb2+r)*40 + cl] = f2b(pv[r]);
      __syncthreads();
    }
  }
  for (int i = t; i < 1024; i += 256) {
    int k = i >> 5, l = i & 31;
    float lb = b2f(LbS[k*40+l]);
    float p2 = b2f(PmS[k*40+l]);
    float p3 = b2f(PmS[1280 + k*40+l]);
    float p4 = b2f(PmS[2560 + k*40+l]);
    float diag = (k == l) ? 1.0f : 0.0f;
#pragma unroll
    for (int j = 0; j < NJ; ++j) {
      float sj = -0.05f * (float)(1 << j);
      float cc2 = 0.5f*sj*sj;
      float cc3 = cc2*sj*(1.0f/3.0f);
      float cc4 = cc3*sj*0.25f;
      psisS[j*1280 + k*40 + l] = f2b(diag + sj*lb + cc2*p2 + cc3*p3 + cc4*p4);
    }
  }

  // ---- depth loop
  for (int d = 0; d < NDEPTH; ++d) {
    // ===== mix: j pairs {0,1},{2,3},{4}
    f32x4 m00 = {0.f,0.f,0.f,0.f}, m01 = m00, m10 = m00, m11 = m00;
    for (int jp = 0; jp < 3; ++jp) {
      const int njp = (jp == 2) ? 1 : 2;
      __syncthreads();                       // HjS free / hbS writes done
      for (int jj = 0; jj < njp; ++jj) {
        int j = 2*jp + jj;
        ushort_t* HjS = (ushort_t*)scratch + jj*5120;  // [128][40]
        const ushort_t* Wp = wpk + (size_t)(d*NJ + j)*16384;
        const float alj = alpha[d*NJ + j];
#pragma unroll
        for (int tni = 0; tni < 2; ++tni) {
          int tn = 2*w + tni;
          f32x4 acc0 = {0.f,0.f,0.f,0.f}, acc1 = acc0;
#pragma unroll
          for (int tk = 0; tk < 4; ++tk) {
            bf16x8 bfr = *(const bf16x8*)(Wp + ((tk*8 + tn) << 9) + (lane << 3));
            int row0 = lo16;
            int ba0 = ((row0 << 8) + (tk << 6) + (hi4 << 4)) ^ ((row0 & 7) << 4);
            bf16x8 a0 = *(const bf16x8*)((const char*)hbS + ba0);
            acc0 = MFMA(a0, bfr, acc0);
            int row1 = 16 + lo16;
            int ba1 = ((row1 << 8) + (tk << 6) + (hi4 << 4)) ^ ((row1 & 7) << 4);
            bf16x8 a1 = *(const bf16x8*)((const char*)hbS + ba1);
            acc1 = MFMA(a1, bfr, acc1);
          }
          int c = tn*16 + lo16;
          int rbase = hi4*4;
#pragma unroll
          for (int r = 0; r < 4; ++r) {
            HjS[c*40 + rbase + r]      = f2b(alj * acc0[r]);
            HjS[c*40 + 16 + rbase + r] = f2b(alj * acc1[r]);
          }
        }
      }
      __syncthreads();
      for (int jj = 0; jj < njp; ++jj) {
        int j = 2*jp + jj;
        const char* psj = (const char*)(psisS + j*1280);
        const char* HjB = (const char*)scratch + jj*10240;
        int koff = hi4 << 4;
        bf16x8 pa0 = *(const bf16x8*)(psj + lo16*80 + koff);
        bf16x8 pa1 = *(const bf16x8*)(psj + (16 + lo16)*80 + koff);
        bf16x8 hb0 = *(const bf16x8*)(HjB + c0*80 + koff);
        bf16x8 hb1 = *(const bf16x8*)(HjB + c1*80 + koff);
        m00 = MFMA(pa0, hb0, m00);
        m01 = MFMA(pa0, hb1, m01);
        m10 = MFMA(pa1, hb0, m10);
        m11 = MFMA(pa1, hb1, m11);
      }
    }
    // ===== u = hc + relu(mix+wb) in regs; LN1 via DPP + rowStat
    float u[2][2][4];
    {
      float wb0 = wb[d*NC + c0], wb1 = wb[d*NC + c1];
#pragma unroll
      for (int r = 0; r < 4; ++r) {
        u[0][0][r] = hc[0][0][r] + fmaxf(m00[r] + wb0, 0.f);
        u[0][1][r] = hc[0][1][r] + fmaxf(m01[r] + wb1, 0.f);
        u[1][0][r] = hc[1][0][r] + fmaxf(m10[r] + wb0, 0.f);
        u[1][1][r] = hc[1][1][r] + fmaxf(m11[r] + wb1, 0.f);
      }
#pragma unroll
      for (int mi = 0; mi < 2; ++mi)
#pragma unroll
        for (int r = 0; r < 4; ++r) {
          float s = u[mi][0][r] + u[mi][1][r];
          float q = u[mi][0][r]*u[mi][0][r] + u[mi][1][r]*u[mi][1][r];
          s = dpp_sum16(s);
          q = dpp_sum16(q);
          if (lo16 == 0) {
            int row = mi*16 + hi4*4 + r;
            rowStat[row*8 + w*2]     = s;
            rowStat[row*8 + w*2 + 1] = q;
          }
        }
    }
    __syncthreads();   // (A) rowStat visible; all waves past mix
    {
      float g0 = ln1g[d*NC + c0], b0 = ln1b[d*NC + c0];
      float g1 = ln1g[d*NC + c1], b1 = ln1b[d*NC + c1];
#pragma unroll
      for (int mi = 0; mi < 2; ++mi)
#pragma unroll
        for (int r = 0; r < 4; ++r) {
          int row = mi*16 + hi4*4 + r;
          f32x4 a = *(const f32x4*)(rowStat + row*8);
          f32x4 bq = *(const f32x4*)(rowStat + row*8 + 4);
          float mu = (a[0]+a[2]+bq[0]+bq[2]) * (1.0f/128.0f);
          float ex2 = (a[1]+a[3]+bq[1]+bq[3]) * (1.0f/128.0f);
          float rs = rsqrtf(ex2 - mu*mu + EPSF);
          float h0 = (u[mi][0][r] - mu)*rs*g0 + b0;
          float h1 = (u[mi][1][r] - mu)*rs*g1 + b1;
          hc[mi][0][r] = h0; hc[mi][1][r] = h1;
          int ha0 = ((row << 8) + (c0 << 1)) ^ ((row & 7) << 4);
          int ha1 = ((row << 8) + (c1 << 1)) ^ ((row & 7) << 4);
          hbS[ha0 >> 1] = f2b(h0);
          hbS[ha1 >> 1] = f2b(h1);
        }
    }
    __syncthreads();   // (B) hbS(LN1) ready, scratch free
    // ===== qkv: 48 tiles, 12/wave
    const ushort_t* Wq = wpk + 163840 + (size_t)d*49152;
#pragma unroll
    for (int ti = 0; ti < 12; ++ti) {
      int tile = w + 4*ti;
      int mi = (tile >= 24) ? 1 : 0;
      int tn = tile - 24*mi;
      int comp = tn >> 3;
      int cb = (tn & 7) * 16;
      f32x4 acc = {0.f,0.f,0.f,0.f};
#pragma unroll
      for (int tk = 0; tk < 4; ++tk) {
        bf16x8 bfr = *(const bf16x8*)(Wq + ((tk*24 + tn) << 9) + (lane << 3));
        int row = mi*16 + lo16;
        int ba = ((row << 8) + (tk << 6) + (hi4 << 4)) ^ ((row & 7) << 4);
        bf16x8 a = *(const bf16x8*)((const char*)hbS + ba);
        acc = MFMA(a, bfr, acc);
      }
      int cl = cb + lo16;
      int rb2 = mi*16 + hi4*4;
      if (comp == 0) {
#pragma unroll
        for (int r = 0; r < 4; ++r) qS[(rb2+r)*136 + cl] = f2b(acc[r]);
      } else if (comp == 1) {
#pragma unroll
        for (int r = 0; r < 4; ++r) kS2[(rb2+r)*136 + cl] = f2b(acc[r]);
      } else {
#pragma unroll
        for (int r = 0; r < 4; ++r) vTS[cl*40 + rb2 + r] = f2b(acc[r]);
      }
    }
    __syncthreads();
    // ===== scores into regs: wave w -> pairs (h,mi) = pi>>1,pi&1 for pi=w,w+4
    float scr[2][2][4];
#pragma unroll
    for (int ti = 0; ti < 2; ++ti) {
      int pi = w + 4*ti;
      int h = pi >> 1, mi = pi & 1;
      int koff = h*64 + (hi4 << 4);
      bf16x8 qa = *(const bf16x8*)((const char*)qS + (mi*16 + lo16)*272 + koff);
#pragma unroll
      for (int ni = 0; ni < 2; ++ni) {
        bf16x8 kb = *(const bf16x8*)((const char*)kS2 + (ni*16 + lo16)*272 + koff);
        f32x4 z = {0.f,0.f,0.f,0.f};
        f32x4 sv = MFMA(qa, kb, z);
#pragma unroll
        for (int r = 0; r < 4; ++r) scr[ti][ni][r] = sv[r] * 0.17677669529663687f;
      }
    }
    __syncthreads();   // q consumed; att may overwrite qS
    // ===== softmax in regs (DPP row reduce), att -> qS
#pragma unroll
    for (int ti = 0; ti < 2; ++ti) {
      int pi = w + 4*ti;
      int h = pi >> 1, mi = pi & 1;
#pragma unroll
      for (int r = 0; r < 4; ++r) {
        float s0 = scr[ti][0][r], s1 = scr[ti][1][r];
        float mx = dpp_max16(fmaxf(s0, s1));
        float e0 = expf(s0 - mx), e1 = expf(s1 - mx);
        float sum = dpp_sum16(e0 + e1);
        float iv = 1.0f / sum;
        int row = mi*16 + hi4*4 + r;
        qS[row*136 + h*32 + lo16]      = f2b(e0*iv);
        qS[row*136 + h*32 + 16 + lo16] = f2b(e1*iv);
      }
    }
    __syncthreads();
    // ===== PV -> hbS (o, bf16 swizzled)
#pragma unroll
    for (int ti = 0; ti < 4; ++ti) {
      int tile = w + 4*ti;
      int h = tile >> 2, mi = (tile >> 1) & 1, ni = tile & 1;
      bf16x8 aa = *(const bf16x8*)((const char*)qS + (mi*16 + lo16)*272 + h*64 + (hi4 << 4));
      bf16x8 vb = *(const bf16x8*)((const char*)vTS + (h*32 + ni*16 + lo16)*80 + (hi4 << 4));
      f32x4 z = {0.f,0.f,0.f,0.f};
      f32x4 ov = MFMA(aa, vb, z);
      int col = h*32 + ni*16 + lo16;
      int rb2 = mi*16 + hi4*4;
#pragma unroll
      for (int r = 0; r < 4; ++r) {
        int row = rb2 + r;
        int ha = ((row << 8) + (col << 1)) ^ ((row & 7) << 4);
        hbS[ha >> 1] = f2b(ov[r]);
      }
    }
    __syncthreads();
    // ===== proj + residual in regs; LN2 via DPP + rowStat
    const ushort_t* Wop = wpk + 262144 + (size_t)d*16384;
#pragma unroll
    for (int tni = 0; tni < 2; ++tni) {
      int tn = 2*w + tni;
      f32x4 acc0 = {0.f,0.f,0.f,0.f}, acc1 = acc0;
#pragma unroll
      for (int tk = 0; tk < 4; ++tk) {
        bf16x8 bfr = *(const bf16x8*)(Wop + ((tk*8 + tn) << 9) + (lane << 3));
        int row0 = lo16;
        int ba0 = ((row0 << 8) + (tk << 6) + (hi4 << 4)) ^ ((row0 & 7) << 4);
        bf16x8 a0 = *(const bf16x8*)((const char*)hbS + ba0);
        acc0 = MFMA(a0, bfr, acc0);
        int row1 = 16 + lo16;
        int ba1 = ((row1 << 8) + (tk << 6) + (hi4 << 4)) ^ ((row1 & 7) << 4);
        bf16x8 a1 = *(const bf16x8*)((const char*)hbS + ba1);
        acc1 = MFMA(a1, bfr, acc1);
      }
#pragma unroll
      for (int r = 0; r < 4; ++r) {
        u[0][tni][r] = hc[0][tni][r] + acc0[r];
        u[1][tni][r] = hc[1][tni][r] + acc1[r];
      }
    }
#pragma unroll
    for (int mi = 0; mi < 2; ++mi)
#pragma unroll
      for (int r = 0; r < 4; ++r) {
        float s = u[mi][0][r] + u[mi][1][r];
        float q = u[mi][0][r]*u[mi][0][r] + u[mi][1][r]*u[mi][1][r];
        s = dpp_sum16(s);
        q = dpp_sum16(q);
        if (lo16 == 0) {
          int row = mi*16 + hi4*4 + r;
          rowStat[row*8 + w*2]     = s;   // vTS dead (all waves past PV barrier)
          rowStat[row*8 + w*2 + 1] = q;
        }
      }
    __syncthreads();   // (C)
    {
      float g0 = ln2g[d*NC + c0], b0 = ln2b[d*NC + c0];
      float g1 = ln2g[d*NC + c1], b1 = ln2b[d*NC + c1];
#pragma unroll
      for (int mi = 0; mi < 2; ++mi)
#pragma unroll
        for (int r = 0; r < 4; ++r) {
          int row = mi*16 + hi4*4 + r;
          f32x4 a = *(const f32x4*)(rowStat + row*8);
          f32x4 bq = *(const f32x4*)(rowStat + row*8 + 4);
          float mu = (a[0]+a[2]+bq[0]+bq[2]) * (1.0f/128.0f);
          float ex2 = (a[1]+a[3]+bq[1]+bq[3]) * (1.0f/128.0f);
          float rs = rsqrtf(ex2 - mu*mu + EPSF);
          float h0 = (u[mi][0][r] - mu)*rs*g0 + b0;
          float h1 = (u[mi][1][r] - mu)*rs*g1 + b1;
          hc[mi][0][r] = h0; hc[mi][1][r] = h1;
          int ha0 = ((row << 8) + (c0 << 1)) ^ ((row & 7) << 4);
          int ha1 = ((row << 8) + (c1 << 1)) ^ ((row & 7) << 4);
          hbS[ha0 >> 1] = f2b(h0);
          hbS[ha1 >> 1] = f2b(h1);
        }
    }
    // next depth's jp-loop barrier (or reg-only maxpool) provides the guard
  }
  // ---- maxpool over K (regs + 2 shfl)
  {
    float v0 = hc[0][0][0], v1 = hc[0][1][0];
#pragma unroll
    for (int r = 1; r < 4; ++r) { v0 = fmaxf(v0, hc[0][0][r]); v1 = fmaxf(v1, hc[0][1][r]); }
#pragma unroll
    for (int r = 0; r < 4; ++r) { v0 = fmaxf(v0, hc[1][0][r]); v1 = fmaxf(v1, hc[1][1][r]); }
    v0 = fmaxf(v0, __shfl_xor(v0, 16)); v0 = fmaxf(v0, __shfl_xor(v0, 32));
    v1 = fmaxf(v1, __shfl_xor(v1, 16)); v1 = fmaxf(v1, __shfl_xor(v1, 32));
    if (hi4 == 0) {
      out[(size_t)p*NC + c0] = v0;
      out[(size_t)p*NC + c1] = v1;
    }
  }
}

// ---------------------------------------------------------------- launcher
extern "C" void kernel_launch(void* const* d_in, const int* in_sizes, int n_in,
                              void* d_out, int out_size, void* d_ws, size_t ws_size,
                              hipStream_t stream) {
  const float* xyz    = (const float*)d_in[0];
  const float* points = (const float*)d_in[1];
  const float* w1     = (const float*)d_in[2];
  const float* g1     = (const float*)d_in[3];
  const float* b1     = (const float*)d_in[4];
  const float* w2     = (const float*)d_in[5];
  const float* g2     = (const float*)d_in[6];
  const float* b2     = (const float*)d_in[7];
  const float* w3     = (const float*)d_in[8];
  const float* g3     = (const float*)d_in[9];
  const float* b3     = (const float*)d_in[10];
  const float* wsW    = (const float*)d_in[11];
  const float* wb     = (const float*)d_in[12];
  const float* alpha  = (const float*)d_in[13];
  const float* wqkv   = (const float*)d_in[14];
  const float* wo     = (const float*)d_in[15];
  const float* ln1g   = (const float*)d_in[16];
  const float* ln1b   = (const float*)d_in[17];
  const float* ln2g   = (const float*)d_in[18];
  const float* ln2b   = (const float*)d_in[19];
  float* outp = (float*)d_out;

  float* wsf   = (float*)d_ws;
  float* gnorm = wsf;                        // 786432 f
  float* stats = wsf + 786432;               // 768 f
  float* aff   = wsf + 787200;               // 768 f
  int*   knn   = (int*)(wsf + 787968);       // 262144 i  (reused as wpk after k_layer1)
  ushort_t* wpk = (ushort_t*)(wsf + 787968); // 294912 bf16
  float* h2    = wsf + 1050112;              // 16777216 f
  float* hX    = wsf + 17827328;             // 33554432 f

  hipMemsetAsync(stats, 0, 768*sizeof(float), stream);
  k_fps<<<NB, 1024, 0, stream>>>(xyz, outp);
  k_knn<<<NPTS, 64, 0, stream>>>(xyz, outp, knn, gnorm);
  k_layer1<<<NM/64, 256, 0, stream>>>(points, knn, gnorm, w1, hX, stats);
  k_pack<<<294912/256, 256, 0, stream>>>(wsW, wqkv, wo, wpk);
  k_finalize<<<1, 128, 0, stream>>>(stats, g1, b1, aff, 64);
  k_layer<64><<<NM/64, 256, 0, stream>>>(hX, aff, w2, h2, stats + 256);
  k_finalize<<<1, 128, 0, stream>>>(stats + 256, g2, b2, aff + 256, 64);
  k_layer<128><<<NM/64, 256, 0, stream>>>(h2, aff + 256, w3, hX, stats + 512);
  k_finalize<<<1, 128, 0, stream>>>(stats + 512, g3, b3, aff + 512, 128);
  k_group<<<NPTS, 256, 0, stream>>>(hX, aff + 512, gnorm, wpk, wb, alpha,
                                    ln1g, ln1b, ln2g, ln2b, outp + (size_t)NB*NS*3);
}

// Round 9
// 1807.202 us; speedup vs baseline: 1.1731x; 1.1492x over previous
//
#include <hip/hip_runtime.h>
#include <math.h>

#define NB 8
#define NP 4096
#define NCIN 64
#define NS 1024
#define NK 32
#define NC 128
#define NJ 5
#define NDEPTH 2
#define NH 4
#define NPTS (NB*NS)       /* 8192 groups */
#define NM (NPTS*NK)       /* 262144 rows */
#define EPSF 1e-5f

typedef float f32x4 __attribute__((ext_vector_type(4)));
typedef short bf16x8 __attribute__((ext_vector_type(8)));
typedef unsigned short ushort_t;
typedef unsigned long long u64;

#define MFMA(a,b,c) __builtin_amdgcn_mfma_f32_16x16x32_bf16(a,b,c,0,0,0)

__device__ __forceinline__ ushort_t f2b(float f) {
  unsigned int u = __float_as_uint(f);
  u = (u + 0x7fffu + ((u >> 16) & 1u)) >> 16;
  return (ushort_t)u;
}
__device__ __forceinline__ float b2f(ushort_t h) {
  unsigned int u = ((unsigned int)h) << 16;
  return __uint_as_float(u);
}

// DPP in-row-of-16 reduce (VALU pipe).
template<int CTRL>
__device__ __forceinline__ float dpp_f(float v) {
  return __int_as_float(__builtin_amdgcn_update_dpp(0, __float_as_int(v), CTRL, 0xf, 0xf, true));
}
__device__ __forceinline__ float dpp_sum16(float v) {
  v += dpp_f<0xB1>(v); v += dpp_f<0x4E>(v);
  v += dpp_f<0x141>(v); v += dpp_f<0x140>(v);
  return v;
}
__device__ __forceinline__ float dpp_max16(float v) {
  v = fmaxf(v, dpp_f<0xB1>(v)); v = fmaxf(v, dpp_f<0x4E>(v));
  v = fmaxf(v, dpp_f<0x141>(v)); v = fmaxf(v, dpp_f<0x140>(v));
  return v;
}

// ---------------------------------------------------------------- FPS (round-6 version, measured 632 us)
#define DPPMAX(CTRL) { \
  unsigned lo2 = (unsigned)__builtin_amdgcn_update_dpp(0, (int)(unsigned)best, CTRL, 0xf, 0xf, true); \
  unsigned hi2 = (unsigned)__builtin_amdgcn_update_dpp(0, (int)(unsigned)(best >> 32), CTRL, 0xf, 0xf, true); \
  u64 o = ((u64)hi2 << 32) | lo2; \
  if (o > best) best = o; }

__global__ __launch_bounds__(256) void k_fps(const float* __restrict__ xyz,
                                             float* __restrict__ newxyz) {
  const int b = blockIdx.x;
  const int t = threadIdx.x;
  const int lane = t & 63;
  const int w = t >> 6;
  __shared__ float Xl[NP*3];
  __shared__ float cenL[NS*3];
  __shared__ u64 slotP[2][4];
  __shared__ __align__(16) float slotC[2][4][4];   // winner coords per wave
  const float* X = xyz + (size_t)b * NP * 3;
  for (int i = t; i < NP*3; i += 256) Xl[i] = X[i];
  __syncthreads();
  float px[16], py[16], pz[16], dist[16];
  unsigned inv[16];
#pragma unroll
  for (int i = 0; i < 16; ++i) {
    int n = t + 256*i;
    px[i] = Xl[3*n]; py[i] = Xl[3*n+1]; pz[i] = Xl[3*n+2];
    dist[i] = 1e10f;
    inv[i] = ~(unsigned)n;
  }
  float cx = Xl[0], cy = Xl[1], cz = Xl[2];   // far = 0 initially
  for (int s = 0; s < NS; ++s) {
    if (t == 0) { cenL[3*s] = cx; cenL[3*s+1] = cy; cenL[3*s+2] = cz; }
    u64 pk[16];
#pragma unroll
    for (int i = 0; i < 16; ++i) {
      float dx = px[i]-cx, dy = py[i]-cy, dz = pz[i]-cz;
      float d = fmaf(dx,dx, fmaf(dy,dy, dz*dz));
      float nd = fminf(dist[i], d);
      dist[i] = nd;
      pk[i] = ((u64)__float_as_uint(nd) << 32) | inv[i];
    }
#pragma unroll
    for (int st = 1; st < 16; st <<= 1)
#pragma unroll
      for (int i = 0; i < 16; i += 2*st)
        pk[i] = pk[i+st] > pk[i] ? pk[i+st] : pk[i];
    u64 best = pk[0];
    DPPMAX(0x111)  // row_shr:1
    DPPMAX(0x112)
    DPPMAX(0x114)
    DPPMAX(0x118)
    DPPMAX(0x142)  // row_bcast15
    DPPMAX(0x143)  // row_bcast31 -> lane 63 has wave max
    if (lane == 63) {
      slotP[s&1][w] = best;
      int bi3 = 3 * (int)(~(unsigned)best);
      slotC[s&1][w][0] = Xl[bi3];
      slotC[s&1][w][1] = Xl[bi3+1];
      slotC[s&1][w][2] = Xl[bi3+2];
    }
    __syncthreads();
    const int par = s & 1;
    u64 s0 = slotP[par][0], s1 = slotP[par][1], s2 = slotP[par][2], s3 = slotP[par][3];
    f32x4 c0v = *(const f32x4*)&slotC[par][0][0];
    f32x4 c1v = *(const f32x4*)&slotC[par][1][0];
    f32x4 c2v = *(const f32x4*)&slotC[par][2][0];
    f32x4 c3v = *(const f32x4*)&slotC[par][3][0];
    u64 m = s0; f32x4 cw = c0v;
    if (s1 > m) { m = s1; cw = c1v; }
    if (s2 > m) { m = s2; cw = c2v; }
    if (s3 > m) { m = s3; cw = c3v; }
    cx = cw[0]; cy = cw[1]; cz = cw[2];
  }
  __syncthreads();
  float* o = newxyz + (size_t)b * NS * 3;
  for (int i = t; i < NS*3; i += 256) o[i] = cenL[i];
}

// ---------------------------------------------------------------- KNN
__global__ __launch_bounds__(64) void k_knn(const float* __restrict__ xyz,
                                            const float* __restrict__ newxyz,
                                            int* __restrict__ knn_idx,
                                            float* __restrict__ gnorm) {
  const int p = blockIdx.x;
  const int b = p >> 10;
  const int lane = threadIdx.x;
  const float* X = xyz + (size_t)b * NP * 3;
  __shared__ float d2[NP];
  float cx = newxyz[3*p], cy = newxyz[3*p+1], cz = newxyz[3*p+2];
  float sc = cx*cx + cy*cy + cz*cz;
#pragma unroll 4
  for (int i = 0; i < NP/64; ++i) {
    int n = lane + 64*i;
    float x = X[3*n], y = X[3*n+1], z = X[3*n+2];
    float sx = x*x + y*y + z*z;
    float dot = cx*x + cy*y + cz*z;
    d2[n] = sc + sx - 2.0f*dot;
  }
  for (int it = 0; it < NK; ++it) {
    float bv = 3.0e38f; int bi = 0x7fffffff;
#pragma unroll 8
    for (int i = 0; i < NP/64; ++i) {
      int n = lane + 64*i;
      float v = d2[n];
      if (v < bv) { bv = v; bi = n; }
    }
#pragma unroll
    for (int off = 32; off; off >>= 1) {
      float ov = __shfl_xor(bv, off);
      int   oi = __shfl_xor(bi, off);
      if (ov < bv || (ov == bv && oi < bi)) { bv = ov; bi = oi; }
    }
    if (lane == 0) {
      d2[bi] = 3.3e38f;
      knn_idx[p*NK + it] = bi;
      float* g = gnorm + ((size_t)p*NK + it)*3;
      g[0] = X[3*bi]   - cx;
      g[1] = X[3*bi+1] - cy;
      g[2] = X[3*bi+2] - cz;
    }
  }
}

// ---------------------------------------------------------------- MLP layer 1 (scalar; gather-bound)
__global__ __launch_bounds__(256) void k_layer1(const float* __restrict__ points,
                                                const int* __restrict__ knn_idx,
                                                const float* __restrict__ gnorm,
                                                const float* __restrict__ w1,
                                                float* __restrict__ y,
                                                float* __restrict__ stats) {
  const int r0 = blockIdx.x * 64;
  const int t = threadIdx.x;
  __shared__ float Xs[64][69];
  __shared__ float Ws[64][69];
  __shared__ int nid[64];
  __shared__ float ps[4][64], pss[4][64];
  if (t < 64) nid[t] = knn_idx[r0 + t];
  __syncthreads();
  for (int idx = t; idx < 64*67; idx += 256) {
    int r = idx / 67, c = idx % 67;
    int row = r0 + r;
    float v;
    if (c < 3) v = gnorm[(size_t)row*3 + c];
    else {
      int bb = row >> 15;
      int n = nid[r];
      v = points[((size_t)bb*NP + n)*NCIN + (c-3)];
    }
    Xs[r][c] = v;
  }
  for (int idx = t; idx < 64*67; idx += 256) {
    int o = idx / 67, c = idx % 67;
    Ws[o][c] = w1[idx];
  }
  __syncthreads();
  const int col = t & 63;
  const int rb  = t >> 6;
  float s1 = 0.f, s2 = 0.f;
  for (int i = 0; i < 16; ++i) {
    int r = rb + 4*i;
    float acc = 0.f;
#pragma unroll
    for (int c = 0; c < 67; ++c) acc += Xs[r][c] * Ws[col][c];
    y[(size_t)(r0 + r)*64 + col] = acc;
    s1 += acc; s2 += acc*acc;
  }
  ps[rb][col] = s1; pss[rb][col] = s2;
  __syncthreads();
  if (t < 64) {
    float a = ps[0][t]+ps[1][t]+ps[2][t]+ps[3][t];
    float q = pss[0][t]+pss[1][t]+pss[2][t]+pss[3][t];
    atomicAdd(&stats[t], a);
    atomicAdd(&stats[64 + t], q);
  }
}

// ---------------------------------------------------------------- MLP layers 2/3 via MFMA
// X: [64 rows][64] bf16 staged (stride 72 shorts = 144B -> 2-way bank, free);
// W: packed B-fragments (K=64 -> 2 MFMA per 16x16 tile). Wave w owns row-block w.
template <int COUT>
__global__ __launch_bounds__(256) void k_layerM(const float* __restrict__ xin,
                                                const float* __restrict__ aff,
                                                const ushort_t* __restrict__ wp,
                                                float* __restrict__ y,
                                                float* __restrict__ stats) {
  const int r0 = blockIdx.x * 64;
  const int t = threadIdx.x;
  const int lane = t & 63;
  const int w = t >> 6;
  const int lo16 = lane & 15;
  const int hi4 = lane >> 4;
  constexpr int NTN = COUT >> 4;
  __shared__ __align__(16) ushort_t XbS[64*72];
  __shared__ float sa[64], sb[64];
  __shared__ float ps[4][COUT], pss[4][COUT];
  if (t < 64) { sa[t] = aff[t]; sb[t] = aff[64 + t]; }
  __syncthreads();
#pragma unroll
  for (int i = 0; i < 16; ++i) {
    int idx = t + 256*i;
    int r = idx >> 6, c = idx & 63;
    float v = xin[(size_t)r0*64 + idx];
    XbS[r*72 + c] = f2b(fmaxf(sa[c]*v + sb[c], 0.0f));
  }
  __syncthreads();
  const int arow = (w*16 + lo16)*72;
  float s1[NTN], s2[NTN];
#pragma unroll
  for (int tn = 0; tn < NTN; ++tn) {
    f32x4 acc = {0.f,0.f,0.f,0.f};
#pragma unroll
    for (int tk = 0; tk < 2; ++tk) {
      bf16x8 a = *(const bf16x8*)(XbS + arow + tk*32 + hi4*8);
      bf16x8 b = *(const bf16x8*)(wp + ((tk*NTN + tn) << 9) + (lane << 3));
      acc = MFMA(a, b, acc);
    }
    int col = tn*16 + lo16;
    int rbase = r0 + w*16 + hi4*4;
    float a1 = 0.f, a2 = 0.f;
#pragma unroll
    for (int r = 0; r < 4; ++r) {
      y[(size_t)(rbase + r)*COUT + col] = acc[r];
      a1 += acc[r]; a2 += acc[r]*acc[r];
    }
    a1 += __shfl_xor(a1, 16); a1 += __shfl_xor(a1, 32);
    a2 += __shfl_xor(a2, 16); a2 += __shfl_xor(a2, 32);
    s1[tn] = a1; s2[tn] = a2;
  }
  if (hi4 == 0) {
#pragma unroll
    for (int tn = 0; tn < NTN; ++tn) {
      ps[w][tn*16 + lo16]  = s1[tn];
      pss[w][tn*16 + lo16] = s2[tn];
    }
  }
  __syncthreads();
  if (t < COUT) {
    atomicAdd(&stats[t],        ps[0][t]+ps[1][t]+ps[2][t]+ps[3][t]);
    atomicAdd(&stats[COUT + t], pss[0][t]+pss[1][t]+pss[2][t]+pss[3][t]);
  }
}

// ---------------------------------------------------------------- BN stats -> affine
__global__ void k_finalize(const float* __restrict__ stats, const float* __restrict__ g,
                           const float* __restrict__ b, float* __restrict__ aff, int cout) {
  int t = threadIdx.x;
  if (t < cout) {
    const float inv = 1.0f / (float)NM;
    float m = stats[t] * inv;
    float var = stats[cout + t] * inv - m*m;
    float a = g[t] * rsqrtf(var + EPSF);
    aff[t] = a;
    aff[cout + t] = b[t] - m * a;
  }
}

// ---------------------------------------------------------------- pack weights (bf16 B-fragment layout)
// [0,163840): ws (10 mats, K=128,N=128)  [163840,262144): wqkv (2, K=128,N=384)
// [262144,294912): wo (2, K=128,N=128)
// [294912,299008): w2 (K=64,N=64, src [n][k] transposed)
// [299008,307200): w3 (K=64,N=128, src [n][k] transposed)
__global__ __launch_bounds__(256) void k_pack(const float* __restrict__ ws,
                                              const float* __restrict__ wqkv,
                                              const float* __restrict__ wo,
                                              const float* __restrict__ w2,
                                              const float* __restrict__ w3,
                                              ushort_t* __restrict__ wpk) {
  int gid = blockIdx.x*256 + threadIdx.x;    // < 307200
  if (gid < 294912) {
    const float* src; int N_; int rem;
    if (gid < 163840)      { int mat = gid >> 14; rem = gid & 16383; src = ws  + (size_t)mat*16384; N_ = 128; }
    else if (gid < 262144) { int g2 = gid - 163840; int d = g2/49152; rem = g2 - d*49152; src = wqkv + (size_t)d*49152; N_ = 384; }
    else                   { int g3 = gid - 262144; int d = g3 >> 14; rem = g3 & 16383;  src = wo  + (size_t)d*16384; N_ = 128; }
    int NTN = N_ >> 4;
    int tile = rem >> 9, r = rem & 511;
    int tk = tile / NTN, tn = tile % NTN;
    int lane2 = r >> 3, jj = r & 7;
    int k = tk*32 + (lane2 >> 4)*8 + jj;
    int n = tn*16 + (lane2 & 15);
    wpk[gid] = f2b(src[(size_t)k*N_ + n]);
  } else if (gid < 299008) {
    int rem = gid - 294912;                  // w2: NTN=4, src[n*64+k]
    int tile = rem >> 9, r = rem & 511;
    int tk = tile >> 2, tn = tile & 3;
    int lane2 = r >> 3, jj = r & 7;
    int k = tk*32 + (lane2 >> 4)*8 + jj;
    int n = tn*16 + (lane2 & 15);
    wpk[gid] = f2b(w2[n*64 + k]);
  } else if (gid < 307200) {
    int rem = gid - 299008;                  // w3: NTN=8, src[n*64+k]
    int tile = rem >> 9, r = rem & 511;
    int tk = tile >> 3, tn = tile & 7;
    int lane2 = r >> 3, jj = r & 7;
    int k = tk*32 + (lane2 >> 4)*8 + jj;
    int n = tn*16 + (lane2 & 15);
    wpk[gid] = f2b(w3[n*64 + k]);
  }
}

// ---------------------------------------------------------------- fused per-group v4b
__global__ __launch_bounds__(256, 2) void k_group(
    const float* __restrict__ h3, const float* __restrict__ aff3,
    const float* __restrict__ gnorm,
    const ushort_t* __restrict__ wpk,
    const float* __restrict__ wb, const float* __restrict__ alpha,
    const float* __restrict__ ln1g, const float* __restrict__ ln1b,
    const float* __restrict__ ln2g, const float* __restrict__ ln2b,
    float* __restrict__ out) {
  const int p = blockIdx.x;
  const int t = threadIdx.x;
  const int lane = t & 63;
  const int w = t >> 6;
  const int lo16 = lane & 15;
  const int hi4 = lane >> 4;

  __shared__ __align__(16) ushort_t hbS[NK*NC];        // 8K bf16 swizzled
  __shared__ __align__(16) ushort_t psisS[5*32*40];    // 12.5K
  __shared__ __align__(16) unsigned char scratch[27648];

  float*    ddAF = (float*)scratch;
  float*    pxF  = (float*)(scratch + 4224);
  float*    dinvF= (float*)(scratch + 4608);
  float*    sigF = (float*)(scratch + 4736);
  ushort_t* LbS  = (ushort_t*)(scratch + 4768);
  ushort_t* PmS  = (ushort_t*)(scratch + 7328);
  ushort_t* qS   = (ushort_t*)scratch;
  ushort_t* kS2  = (ushort_t*)(scratch + 8704);
  ushort_t* vTS  = (ushort_t*)(scratch + 17408);
  float*    rowStat = (float*)(scratch + 20480);

  const int c0 = 32*w + lo16, c1 = c0 + 16;

  if (t < 96) pxF[t] = gnorm[(size_t)p*96 + t];
  const float* h3p = h3 + (size_t)p*4096;
#pragma unroll
  for (int i = 0; i < 16; ++i) {
    int idx = t + 256*i;
    int c = idx & 127, row = idx >> 7;
    float v = fmaxf(aff3[c]*h3p[idx] + aff3[128+c], 0.f);
    int ha = ((row << 8) + (c << 1)) ^ ((row & 7) << 4);
    hbS[ha >> 1] = f2b(v);
  }
  float hc[2][2][4];
  {
    float ga0 = aff3[c0], gb0 = aff3[128+c0];
    float ga1 = aff3[c1], gb1 = aff3[128+c1];
#pragma unroll
    for (int mi = 0; mi < 2; ++mi)
#pragma unroll
      for (int r = 0; r < 4; ++r) {
        int row = mi*16 + hi4*4 + r;
        hc[mi][0][r] = fmaxf(ga0*h3p[row*NC + c0] + gb0, 0.f);
        hc[mi][1][r] = fmaxf(ga1*h3p[row*NC + c1] + gb1, 0.f);
      }
  }
  __syncthreads();
  for (int i = t; i < 1024; i += 256) {
    int k = i >> 5, l = i & 31;
    float dx = pxF[k*3]  -pxF[l*3];
    float dy = pxF[k*3+1]-pxF[l*3+1];
    float dz = pxF[k*3+2]-pxF[l*3+2];
    ddAF[k*33+l] = dx*dx + dy*dy + dz*dz;
  }
  __syncthreads();
  float part = 0.f;
  for (int i = t; i < 1024; i += 256) part += sqrtf(ddAF[(i>>5)*33 + (i&31)] + 1e-12f);
#pragma unroll
  for (int off = 32; off; off >>= 1) part += __shfl_xor(part, off);
  if (lane == 0) sigF[w] = part;
  __syncthreads();
  if (t == 0) {
    float sg = (sigF[0]+sigF[1]+sigF[2]+sigF[3]) * (1.0f/1024.0f);
    sigF[4] = 2.0f*sg*sg + 1e-12f;
  }
  __syncthreads();
  const float denom = sigF[4];
  for (int i = t; i < 1024; i += 256) {
    int k = i >> 5, l = i & 31;
    ddAF[k*33+l] = expf(-ddAF[k*33+l] / denom);
  }
  __syncthreads();
  if (t < 32) {
    float s = 0.f;
    for (int l = 0; l < 32; ++l) s += ddAF[t*33 + l];
    dinvF[t] = rsqrtf(s + 1e-12f);
  }
  __syncthreads();
  for (int i = t; i < 1024; i += 256) {
    int k = i >> 5, l = i & 31;
    float v = -(dinvF[k] * ddAF[k*33+l] * dinvF[l]);
    if (k == l) v += 1.0f;
    LbS[k*40+l] = f2b(v);
  }
  __syncthreads();
  {
    int mi2 = w >> 1, ni2 = w & 1;
    int arow = (mi2*16 + lo16)*80 + (hi4 << 4);
    int brow = (ni2*16 + lo16)*80 + (hi4 << 4);
    bf16x8 bfr = *(const bf16x8*)((const char*)LbS + brow);
#pragma unroll
    for (int m = 2; m <= 4; ++m) {
      const ushort_t* Asrc = (m == 2) ? LbS : (PmS + (m-3)*1280);
      bf16x8 afr = *(const bf16x8*)((const char*)Asrc + arow);
      f32x4 z = {0.f,0.f,0.f,0.f};
      f32x4 pv = MFMA(afr, bfr, z);
      int rb2 = mi2*16 + hi4*4;
      int cl = ni2*16 + lo16;
#pragma unroll
      for (int r = 0; r < 4; ++r) PmS[(m-2)*1280 + (rb2+r)*40 + cl] = f2b(pv[r]);
      __syncthreads();
    }
  }
  for (int i = t; i < 1024; i += 256) {
    int k = i >> 5, l = i & 31;
    float lb = b2f(LbS[k*40+l]);
    float p2 = b2f(PmS[k*40+l]);
    float p3 = b2f(PmS[1280 + k*40+l]);
    float p4 = b2f(PmS[2560 + k*40+l]);
    float diag = (k == l) ? 1.0f : 0.0f;
#pragma unroll
    for (int j = 0; j < NJ; ++j) {
      float sj = -0.05f * (float)(1 << j);
      float cc2 = 0.5f*sj*sj;
      float cc3 = cc2*sj*(1.0f/3.0f);
      float cc4 = cc3*sj*0.25f;
      psisS[j*1280 + k*40 + l] = f2b(diag + sj*lb + cc2*p2 + cc3*p3 + cc4*p4);
    }
  }

  for (int d = 0; d < NDEPTH; ++d) {
    f32x4 m00 = {0.f,0.f,0.f,0.f}, m01 = m00, m10 = m00, m11 = m00;
    for (int jp = 0; jp < 3; ++jp) {
      const int njp = (jp == 2) ? 1 : 2;
      __syncthreads();
      for (int jj = 0; jj < njp; ++jj) {
        int j = 2*jp + jj;
        ushort_t* HjS = (ushort_t*)scratch + jj*5120;
        const ushort_t* Wp = wpk + (size_t)(d*NJ + j)*16384;
        const float alj = alpha[d*NJ + j];
#pragma unroll
        for (int tni = 0; tni < 2; ++tni) {
          int tn = 2*w + tni;
          f32x4 acc0 = {0.f,0.f,0.f,0.f}, acc1 = acc0;
#pragma unroll
          for (int tk = 0; tk < 4; ++tk) {
            bf16x8 bfr = *(const bf16x8*)(Wp + ((tk*8 + tn) << 9) + (lane << 3));
            int row0 = lo16;
            int ba0 = ((row0 << 8) + (tk << 6) + (hi4 << 4)) ^ ((row0 & 7) << 4);
            bf16x8 a0 = *(const bf16x8*)((const char*)hbS + ba0);
            acc0 = MFMA(a0, bfr, acc0);
            int row1 = 16 + lo16;
            int ba1 = ((row1 << 8) + (tk << 6) + (hi4 << 4)) ^ ((row1 & 7) << 4);
            bf16x8 a1 = *(const bf16x8*)((const char*)hbS + ba1);
            acc1 = MFMA(a1, bfr, acc1);
          }
          int c = tn*16 + lo16;
          int rbase = hi4*4;
#pragma unroll
          for (int r = 0; r < 4; ++r) {
            HjS[c*40 + rbase + r]      = f2b(alj * acc0[r]);
            HjS[c*40 + 16 + rbase + r] = f2b(alj * acc1[r]);
          }
        }
      }
      __syncthreads();
      for (int jj = 0; jj < njp; ++jj) {
        int j = 2*jp + jj;
        const char* psj = (const char*)(psisS + j*1280);
        const char* HjB = (const char*)scratch + jj*10240;
        int koff = hi4 << 4;
        bf16x8 pa0 = *(const bf16x8*)(psj + lo16*80 + koff);
        bf16x8 pa1 = *(const bf16x8*)(psj + (16 + lo16)*80 + koff);
        bf16x8 hb0 = *(const bf16x8*)(HjB + c0*80 + koff);
        bf16x8 hb1 = *(const bf16x8*)(HjB + c1*80 + koff);
        m00 = MFMA(pa0, hb0, m00);
        m01 = MFMA(pa0, hb1, m01);
        m10 = MFMA(pa1, hb0, m10);
        m11 = MFMA(pa1, hb1, m11);
      }
    }
    float u[2][2][4];
    {
      float wb0 = wb[d*NC + c0], wb1 = wb[d*NC + c1];
#pragma unroll
      for (int r = 0; r < 4; ++r) {
        u[0][0][r] = hc[0][0][r] + fmaxf(m00[r] + wb0, 0.f);
        u[0][1][r] = hc[0][1][r] + fmaxf(m01[r] + wb1, 0.f);
        u[1][0][r] = hc[1][0][r] + fmaxf(m10[r] + wb0, 0.f);
        u[1][1][r] = hc[1][1][r] + fmaxf(m11[r] + wb1, 0.f);
      }
#pragma unroll
      for (int mi = 0; mi < 2; ++mi)
#pragma unroll
        for (int r = 0; r < 4; ++r) {
          float s = u[mi][0][r] + u[mi][1][r];
          float q = u[mi][0][r]*u[mi][0][r] + u[mi][1][r]*u[mi][1][r];
          s = dpp_sum16(s);
          q = dpp_sum16(q);
          if (lo16 == 0) {
            int row = mi*16 + hi4*4 + r;
            rowStat[row*8 + w*2]     = s;
            rowStat[row*8 + w*2 + 1] = q;
          }
        }
    }
    __syncthreads();
    {
      float g0 = ln1g[d*NC + c0], b0 = ln1b[d*NC + c0];
      float g1 = ln1g[d*NC + c1], b1 = ln1b[d*NC + c1];
#pragma unroll
      for (int mi = 0; mi < 2; ++mi)
#pragma unroll
        for (int r = 0; r < 4; ++r) {
          int row = mi*16 + hi4*4 + r;
          f32x4 a = *(const f32x4*)(rowStat + row*8);
          f32x4 bq = *(const f32x4*)(rowStat + row*8 + 4);
          float mu = (a[0]+a[2]+bq[0]+bq[2]) * (1.0f/128.0f);
          float ex2 = (a[1]+a[3]+bq[1]+bq[3]) * (1.0f/128.0f);
          float rs = rsqrtf(ex2 - mu*mu + EPSF);
          float h0 = (u[mi][0][r] - mu)*rs*g0 + b0;
          float h1 = (u[mi][1][r] - mu)*rs*g1 + b1;
          hc[mi][0][r] = h0; hc[mi][1][r] = h1;
          int ha0 = ((row << 8) + (c0 << 1)) ^ ((row & 7) << 4);
          int ha1 = ((row << 8) + (c1 << 1)) ^ ((row & 7) << 4);
          hbS[ha0 >> 1] = f2b(h0);
          hbS[ha1 >> 1] = f2b(h1);
        }
    }
    __syncthreads();
    const ushort_t* Wq = wpk + 163840 + (size_t)d*49152;
#pragma unroll
    for (int ti = 0; ti < 12; ++ti) {
      int tile = w + 4*ti;
      int mi = (tile >= 24) ? 1 : 0;
      int tn = tile - 24*mi;
      int comp = tn >> 3;
      int cb = (tn & 7) * 16;
      f32x4 acc = {0.f,0.f,0.f,0.f};
#pragma unroll
      for (int tk = 0; tk < 4; ++tk) {
        bf16x8 bfr = *(const bf16x8*)(Wq + ((tk*24 + tn) << 9) + (lane << 3));
        int row = mi*16 + lo16;
        int ba = ((row << 8) + (tk << 6) + (hi4 << 4)) ^ ((row & 7) << 4);
        bf16x8 a = *(const bf16x8*)((const char*)hbS + ba);
        acc = MFMA(a, bfr, acc);
      }
      int cl = cb + lo16;
      int rb2 = mi*16 + hi4*4;
      if (comp == 0) {
#pragma unroll
        for (int r = 0; r < 4; ++r) qS[(rb2+r)*136 + cl] = f2b(acc[r]);
      } else if (comp == 1) {
#pragma unroll
        for (int r = 0; r < 4; ++r) kS2[(rb2+r)*136 + cl] = f2b(acc[r]);
      } else {
#pragma unroll
        for (int r = 0; r < 4; ++r) vTS[cl*40 + rb2 + r] = f2b(acc[r]);
      }
    }
    __syncthreads();
    float scr[2][2][4];
#pragma unroll
    for (int ti = 0; ti < 2; ++ti) {
      int pi = w + 4*ti;
      int h = pi >> 1, mi = pi & 1;
      int koff = h*64 + (hi4 << 4);
      bf16x8 qa = *(const bf16x8*)((const char*)qS + (mi*16 + lo16)*272 + koff);
#pragma unroll
      for (int ni = 0; ni < 2; ++ni) {
        bf16x8 kb = *(const bf16x8*)((const char*)kS2 + (ni*16 + lo16)*272 + koff);
        f32x4 z = {0.f,0.f,0.f,0.f};
        f32x4 sv = MFMA(qa, kb, z);
#pragma unroll
        for (int r = 0; r < 4; ++r) scr[ti][ni][r] = sv[r] * 0.17677669529663687f;
      }
    }
    __syncthreads();
#pragma unroll
    for (int ti = 0; ti < 2; ++ti) {
      int pi = w + 4*ti;
      int h = pi >> 1, mi = pi & 1;
#pragma unroll
      for (int r = 0; r < 4; ++r) {
        float s0 = scr[ti][0][r], s1 = scr[ti][1][r];
        float mx = dpp_max16(fmaxf(s0, s1));
        float e0 = expf(s0 - mx), e1 = expf(s1 - mx);
        float sum = dpp_sum16(e0 + e1);
        float iv = 1.0f / sum;
        int row = mi*16 + hi4*4 + r;
        qS[row*136 + h*32 + lo16]      = f2b(e0*iv);
        qS[row*136 + h*32 + 16 + lo16] = f2b(e1*iv);
      }
    }
    __syncthreads();
#pragma unroll
    for (int ti = 0; ti < 4; ++ti) {
      int tile = w + 4*ti;
      int h = tile >> 2, mi = (tile >> 1) & 1, ni = tile & 1;
      bf16x8 aa = *(const bf16x8*)((const char*)qS + (mi*16 + lo16)*272 + h*64 + (hi4 << 4));
      bf16x8 vb = *(const bf16x8*)((const char*)vTS + (h*32 + ni*16 + lo16)*80 + (hi4 << 4));
      f32x4 z = {0.f,0.f,0.f,0.f};
      f32x4 ov = MFMA(aa, vb, z);
      int col = h*32 + ni*16 + lo16;
      int rb2 = mi*16 + hi4*4;
#pragma unroll
      for (int r = 0; r < 4; ++r) {
        int row = rb2 + r;
        int ha = ((row << 8) + (col << 1)) ^ ((row & 7) << 4);
        hbS[ha >> 1] = f2b(ov[r]);
      }
    }
    __syncthreads();
    const ushort_t* Wop = wpk + 262144 + (size_t)d*16384;
#pragma unroll
    for (int tni = 0; tni < 2; ++tni) {
      int tn = 2*w + tni;
      f32x4 acc0 = {0.f,0.f,0.f,0.f}, acc1 = acc0;
#pragma unroll
      for (int tk = 0; tk < 4; ++tk) {
        bf16x8 bfr = *(const bf16x8*)(Wop + ((tk*8 + tn) << 9) + (lane << 3));
        int row0 = lo16;
        int ba0 = ((row0 << 8) + (tk << 6) + (hi4 << 4)) ^ ((row0 & 7) << 4);
        bf16x8 a0 = *(const bf16x8*)((const char*)hbS + ba0);
        acc0 = MFMA(a0, bfr, acc0);
        int row1 = 16 + lo16;
        int ba1 = ((row1 << 8) + (tk << 6) + (hi4 << 4)) ^ ((row1 & 7) << 4);
        bf16x8 a1 = *(const bf16x8*)((const char*)hbS + ba1);
        acc1 = MFMA(a1, bfr, acc1);
      }
#pragma unroll
      for (int r = 0; r < 4; ++r) {
        u[0][tni][r] = hc[0][tni][r] + acc0[r];
        u[1][tni][r] = hc[1][tni][r] + acc1[r];
      }
    }
#pragma unroll
    for (int mi = 0; mi < 2; ++mi)
#pragma unroll
      for (int r = 0; r < 4; ++r) {
        float s = u[mi][0][r] + u[mi][1][r];
        float q = u[mi][0][r]*u[mi][0][r] + u[mi][1][r]*u[mi][1][r];
        s = dpp_sum16(s);
        q = dpp_sum16(q);
        if (lo16 == 0) {
          int row = mi*16 + hi4*4 + r;
          rowStat[row*8 + w*2]     = s;
          rowStat[row*8 + w*2 + 1] = q;
        }
      }
    __syncthreads();
    {
      float g0 = ln2g[d*NC + c0], b0 = ln2b[d*NC + c0];
      float g1 = ln2g[d*NC + c1], b1 = ln2b[d*NC + c1];
#pragma unroll
      for (int mi = 0; mi < 2; ++mi)
#pragma unroll
        for (int r = 0; r < 4; ++r) {
          int row = mi*16 + hi4*4 + r;
          f32x4 a = *(const f32x4*)(rowStat + row*8);
          f32x4 bq = *(const f32x4*)(rowStat + row*8 + 4);
          float mu = (a[0]+a[2]+bq[0]+bq[2]) * (1.0f/128.0f);
          float ex2 = (a[1]+a[3]+bq[1]+bq[3]) * (1.0f/128.0f);
          float rs = rsqrtf(ex2 - mu*mu + EPSF);
          float h0 = (u[mi][0][r] - mu)*rs*g0 + b0;
          float h1 = (u[mi][1][r] - mu)*rs*g1 + b1;
          hc[mi][0][r] = h0; hc[mi][1][r] = h1;
          int ha0 = ((row << 8) + (c0 << 1)) ^ ((row & 7) << 4);
          int ha1 = ((row << 8) + (c1 << 1)) ^ ((row & 7) << 4);
          hbS[ha0 >> 1] = f2b(h0);
          hbS[ha1 >> 1] = f2b(h1);
        }
    }
  }
  {
    float v0 = hc[0][0][0], v1 = hc[0][1][0];
#pragma unroll
    for (int r = 1; r < 4; ++r) { v0 = fmaxf(v0, hc[0][0][r]); v1 = fmaxf(v1, hc[0][1][r]); }
#pragma unroll
    for (int r = 0; r < 4; ++r) { v0 = fmaxf(v0, hc[1][0][r]); v1 = fmaxf(v1, hc[1][1][r]); }
    v0 = fmaxf(v0, __shfl_xor(v0, 16)); v0 = fmaxf(v0, __shfl_xor(v0, 32));
    v1 = fmaxf(v1, __shfl_xor(v1, 16)); v1 = fmaxf(v1, __shfl_xor(v1, 32));
    if (hi4 == 0) {
      out[(size_t)p*NC + c0] = v0;
      out[(size_t)p*NC + c1] = v1;
    }
  }
}

// ---------------------------------------------------------------- launcher
extern "C" void kernel_launch(void* const* d_in, const int* in_sizes, int n_in,
                              void* d_out, int out_size, void* d_ws, size_t ws_size,
                              hipStream_t stream) {
  const float* xyz    = (const float*)d_in[0];
  const float* points = (const float*)d_in[1];
  const float* w1     = (const float*)d_in[2];
  const float* g1     = (const float*)d_in[3];
  const float* b1     = (const float*)d_in[4];
  const float* w2     = (const float*)d_in[5];
  const float* g2     = (const float*)d_in[6];
  const float* b2     = (const float*)d_in[7];
  const float* w3     = (const float*)d_in[8];
  const float* g3     = (const float*)d_in[9];
  const float* b3     = (const float*)d_in[10];
  const float* wsW    = (const float*)d_in[11];
  const float* wb     = (const float*)d_in[12];
  const float* alpha  = (const float*)d_in[13];
  const float* wqkv   = (const float*)d_in[14];
  const float* wo     = (const float*)d_in[15];
  const float* ln1g   = (const float*)d_in[16];
  const float* ln1b   = (const float*)d_in[17];
  const float* ln2g   = (const float*)d_in[18];
  const float* ln2b   = (const float*)d_in[19];
  float* outp = (float*)d_out;

  float* wsf   = (float*)d_ws;
  float* gnorm = wsf;                        // 786432 f
  float* stats = wsf + 786432;               // 768 f
  float* aff   = wsf + 787200;               // 768 f
  int*   knn   = (int*)(wsf + 787968);       // 262144 i (reused as wpk after k_layer1)
  ushort_t* wpk = (ushort_t*)(wsf + 787968); // 307200 bf16 = 614400 B (fits knn's 1 MB)
  float* h2    = wsf + 1050112;              // 16777216 f
  float* hX    = wsf + 17827328;             // 33554432 f

  hipMemsetAsync(stats, 0, 768*sizeof(float), stream);
  k_fps<<<NB, 256, 0, stream>>>(xyz, outp);
  k_knn<<<NPTS, 64, 0, stream>>>(xyz, outp, knn, gnorm);
  k_layer1<<<NM/64, 256, 0, stream>>>(points, knn, gnorm, w1, hX, stats);
  k_pack<<<307200/256, 256, 0, stream>>>(wsW, wqkv, wo, w2, w3, wpk);
  k_finalize<<<1, 128, 0, stream>>>(stats, g1, b1, aff, 64);
  k_layerM<64><<<NM/64, 256, 0, stream>>>(hX, aff, wpk + 294912, h2, stats + 256);
  k_finalize<<<1, 128, 0, stream>>>(stats + 256, g2, b2, aff + 256, 64);
  k_layerM<128><<<NM/64, 256, 0, stream>>>(h2, aff + 256, wpk + 299008, hX, stats + 512);
  k_finalize<<<1, 128, 0, stream>>>(stats + 512, g3, b3, aff + 512, 128);
  k_group<<<NPTS, 256, 0, stream>>>(hX, aff + 512, gnorm, wpk, wb, alpha,
                                    ln1g, ln1b, ln2g, ln2b, outp + (size_t)NB*NS*3);
}

// Round 11
// 1756.431 us; speedup vs baseline: 1.2070x; 1.0289x over previous
//
#include <hip/hip_runtime.h>
#include <math.h>

#define NB 8
#define NP 4096
#define NCIN 64
#define NS 1024
#define NK 32
#define NC 128
#define NJ 5
#define NDEPTH 2
#define NH 4
#define NPTS (NB*NS)       /* 8192 groups */
#define NM (NPTS*NK)       /* 262144 rows */
#define EPSF 1e-5f

typedef float f32x4 __attribute__((ext_vector_type(4)));
typedef short bf16x8 __attribute__((ext_vector_type(8)));
typedef unsigned short ushort_t;
typedef unsigned long long u64;

#define MFMA(a,b,c) __builtin_amdgcn_mfma_f32_16x16x32_bf16(a,b,c,0,0,0)

__device__ __forceinline__ ushort_t f2b(float f) {
  unsigned int u = __float_as_uint(f);
  u = (u + 0x7fffu + ((u >> 16) & 1u)) >> 16;
  return (ushort_t)u;
}
__device__ __forceinline__ float b2f(ushort_t h) {
  unsigned int u = ((unsigned int)h) << 16;
  return __uint_as_float(u);
}

// DPP in-row-of-16 reduce (VALU pipe).
template<int CTRL>
__device__ __forceinline__ float dpp_f(float v) {
  return __int_as_float(__builtin_amdgcn_update_dpp(0, __float_as_int(v), CTRL, 0xf, 0xf, true));
}
__device__ __forceinline__ float dpp_sum16(float v) {
  v += dpp_f<0xB1>(v); v += dpp_f<0x4E>(v);
  v += dpp_f<0x141>(v); v += dpp_f<0x140>(v);
  return v;
}
__device__ __forceinline__ float dpp_max16(float v) {
  v = fmaxf(v, dpp_f<0xB1>(v)); v = fmaxf(v, dpp_f<0x4E>(v));
  v = fmaxf(v, dpp_f<0x141>(v)); v = fmaxf(v, dpp_f<0x140>(v));
  return v;
}

// ---------------------------------------------------------------- FPS (round-6 version)
#define DPPMAX(CTRL) { \
  unsigned lo2 = (unsigned)__builtin_amdgcn_update_dpp(0, (int)(unsigned)best, CTRL, 0xf, 0xf, true); \
  unsigned hi2 = (unsigned)__builtin_amdgcn_update_dpp(0, (int)(unsigned)(best >> 32), CTRL, 0xf, 0xf, true); \
  u64 o = ((u64)hi2 << 32) | lo2; \
  if (o > best) best = o; }

// min-reduce: invalid lanes keep OLD value (identity for min)
#define DPPMIN(CTRL) { \
  unsigned lo2 = (unsigned)__builtin_amdgcn_update_dpp((int)(unsigned)best, (int)(unsigned)best, CTRL, 0xf, 0xf, false); \
  unsigned hi2 = (unsigned)__builtin_amdgcn_update_dpp((int)(unsigned)(best >> 32), (int)(unsigned)(best >> 32), CTRL, 0xf, 0xf, false); \
  u64 o = ((u64)hi2 << 32) | lo2; \
  if (o < best) best = o; }

__global__ __launch_bounds__(256) void k_fps(const float* __restrict__ xyz,
                                             float* __restrict__ newxyz) {
  const int b = blockIdx.x;
  const int t = threadIdx.x;
  const int lane = t & 63;
  const int w = t >> 6;
  __shared__ float Xl[NP*3];
  __shared__ float cenL[NS*3];
  __shared__ u64 slotP[2][4];
  __shared__ __align__(16) float slotC[2][4][4];
  const float* X = xyz + (size_t)b * NP * 3;
  for (int i = t; i < NP*3; i += 256) Xl[i] = X[i];
  __syncthreads();
  float px[16], py[16], pz[16], dist[16];
  unsigned inv[16];
#pragma unroll
  for (int i = 0; i < 16; ++i) {
    int n = t + 256*i;
    px[i] = Xl[3*n]; py[i] = Xl[3*n+1]; pz[i] = Xl[3*n+2];
    dist[i] = 1e10f;
    inv[i] = ~(unsigned)n;
  }
  float cx = Xl[0], cy = Xl[1], cz = Xl[2];
  for (int s = 0; s < NS; ++s) {
    if (t == 0) { cenL[3*s] = cx; cenL[3*s+1] = cy; cenL[3*s+2] = cz; }
    u64 pk[16];
#pragma unroll
    for (int i = 0; i < 16; ++i) {
      float dx = px[i]-cx, dy = py[i]-cy, dz = pz[i]-cz;
      float d = fmaf(dx,dx, fmaf(dy,dy, dz*dz));   // sum of squares: >= 0, raw-bit order OK
      float nd = fminf(dist[i], d);
      dist[i] = nd;
      pk[i] = ((u64)__float_as_uint(nd) << 32) | inv[i];
    }
#pragma unroll
    for (int st = 1; st < 16; st <<= 1)
#pragma unroll
      for (int i = 0; i < 16; i += 2*st)
        pk[i] = pk[i+st] > pk[i] ? pk[i+st] : pk[i];
    u64 best = pk[0];
    DPPMAX(0x111)
    DPPMAX(0x112)
    DPPMAX(0x114)
    DPPMAX(0x118)
    DPPMAX(0x142)
    DPPMAX(0x143)
    if (lane == 63) {
      slotP[s&1][w] = best;
      int bi3 = 3 * (int)(~(unsigned)best);
      slotC[s&1][w][0] = Xl[bi3];
      slotC[s&1][w][1] = Xl[bi3+1];
      slotC[s&1][w][2] = Xl[bi3+2];
    }
    __syncthreads();
    const int par = s & 1;
    u64 s0 = slotP[par][0], s1 = slotP[par][1], s2 = slotP[par][2], s3 = slotP[par][3];
    f32x4 c0v = *(const f32x4*)&slotC[par][0][0];
    f32x4 c1v = *(const f32x4*)&slotC[par][1][0];
    f32x4 c2v = *(const f32x4*)&slotC[par][2][0];
    f32x4 c3v = *(const f32x4*)&slotC[par][3][0];
    u64 m = s0; f32x4 cw = c0v;
    if (s1 > m) { m = s1; cw = c1v; }
    if (s2 > m) { m = s2; cw = c2v; }
    if (s3 > m) { m = s3; cw = c3v; }
    cx = cw[0]; cy = cw[1]; cz = cw[2];
  }
  __syncthreads();
  float* o = newxyz + (size_t)b * NS * 3;
  for (int i = t; i < NS*3; i += 256) o[i] = cenL[i];
}

// ---------------------------------------------------------------- KNN (DPP min-reduce, ORDER-PRESERVING KEY)
// d2 = sc+sx-2*dot can be NEGATIVE (query point is in the cloud) — raw float
// bits are not unsigned-order-isomorphic for negatives (r10 bug, absmax 3.4).
// Monotone key: u ^= (u>>31 ? 0xFFFFFFFF : 0x80000000).
__global__ __launch_bounds__(64) void k_knn(const float* __restrict__ xyz,
                                            const float* __restrict__ newxyz,
                                            int* __restrict__ knn_idx,
                                            float* __restrict__ gnorm) {
  const int p = blockIdx.x;
  const int b = p >> 10;
  const int lane = threadIdx.x;
  const float* X = xyz + (size_t)b * NP * 3;
  __shared__ float d2[NP];
  float cx = newxyz[3*p], cy = newxyz[3*p+1], cz = newxyz[3*p+2];
  float sc = cx*cx + cy*cy + cz*cz;
#pragma unroll 4
  for (int i = 0; i < NP/64; ++i) {
    int n = lane + 64*i;
    float x = X[3*n], y = X[3*n+1], z = X[3*n+2];
    float sx = x*x + y*y + z*z;
    float dot = cx*x + cy*y + cz*z;
    d2[n] = sc + sx - 2.0f*dot;
  }
  for (int it = 0; it < NK; ++it) {
    float bv = 3.0e38f; int bi = 0x7fffffff;
#pragma unroll 8
    for (int i = 0; i < NP/64; ++i) {
      int n = lane + 64*i;
      float v = d2[n];
      if (v < bv) { bv = v; bi = n; }   // ascending n per lane: lowest idx on ties
    }
    unsigned ub = __float_as_uint(bv);
    ub ^= ((unsigned)((int)ub >> 31)) | 0x80000000u;   // float order -> unsigned order
    u64 best = ((u64)ub << 32) | (unsigned)bi;
    DPPMIN(0x111)
    DPPMIN(0x112)
    DPPMIN(0x114)
    DPPMIN(0x118)
    DPPMIN(0x142)
    DPPMIN(0x143)   // lane 63 holds wave min
    u64 win = __shfl(best, 63);
    if (lane == 0) {
      int wi = (int)(unsigned)win;
      d2[wi] = 3.3e38f;
      knn_idx[p*NK + it] = wi;
      float* g = gnorm + ((size_t)p*NK + it)*3;
      g[0] = X[3*wi]   - cx;
      g[1] = X[3*wi+1] - cy;
      g[2] = X[3*wi+2] - cz;
    }
  }
}

// ---------------------------------------------------------------- pack w1 B-fragments (K=67 zero-padded to 96, N=64)
__global__ __launch_bounds__(256) void k_pack1(const float* __restrict__ w1,
                                               ushort_t* __restrict__ wp) {
  int gid = blockIdx.x*256 + threadIdx.x;    // < 6144 (12 tiles x 512)
  int tile = gid >> 9, r = gid & 511;
  int tk = tile >> 2, tn = tile & 3;
  int lane2 = r >> 3, jj = r & 7;
  int k = tk*32 + (lane2 >> 4)*8 + jj;
  int n = tn*16 + (lane2 & 15);
  float v = (k < 67) ? w1[n*67 + k] : 0.0f;   // w1 is [out=64][in=67]
  wp[gid] = f2b(v);
}

// ---------------------------------------------------------------- MLP layer 1 via MFMA (gather + K=96)
__global__ __launch_bounds__(256) void k_layer1M(const float* __restrict__ points,
                                                 const int* __restrict__ knn_idx,
                                                 const float* __restrict__ gnorm,
                                                 const ushort_t* __restrict__ wp1,
                                                 float* __restrict__ y,
                                                 float* __restrict__ stats) {
  const int r0 = blockIdx.x * 64;
  const int t = threadIdx.x;
  const int lane = t & 63;
  const int w = t >> 6;
  const int lo16 = lane & 15;
  const int hi4 = lane >> 4;
  __shared__ __align__(16) ushort_t XbS[64*104];   // rows x (96 + 8 pad), stride 208B
  __shared__ int nid[64];
  __shared__ float ps[4][64], pss[4][64];
  if (t < 64) nid[t] = knn_idx[r0 + t];
  __syncthreads();
  for (int idx = t; idx < 64*67; idx += 256) {
    int r = idx / 67, c = idx % 67;
    int row = r0 + r;
    float v;
    if (c < 3) v = gnorm[(size_t)row*3 + c];
    else {
      int bb = row >> 15;
      int n = nid[r];
      v = points[((size_t)bb*NP + n)*NCIN + (c-3)];
    }
    XbS[r*104 + c] = f2b(v);
  }
  for (int idx = t; idx < 64*37; idx += 256) {   // zero cols 67..103
    int r = idx / 37, c = idx % 37;
    XbS[r*104 + 67 + c] = 0;
  }
  __syncthreads();
  const int arow = (w*16 + lo16)*104;
  float s1[4], s2[4];
#pragma unroll
  for (int tn = 0; tn < 4; ++tn) {
    f32x4 acc = {0.f,0.f,0.f,0.f};
#pragma unroll
    for (int tk = 0; tk < 3; ++tk) {
      bf16x8 a = *(const bf16x8*)(XbS + arow + tk*32 + hi4*8);
      bf16x8 b = *(const bf16x8*)(wp1 + ((tk*4 + tn) << 9) + (lane << 3));
      acc = MFMA(a, b, acc);
    }
    int col = tn*16 + lo16;
    int rbase = r0 + w*16 + hi4*4;
    float a1 = 0.f, a2 = 0.f;
#pragma unroll
    for (int r = 0; r < 4; ++r) {
      y[(size_t)(rbase + r)*64 + col] = acc[r];
      a1 += acc[r]; a2 += acc[r]*acc[r];
    }
    a1 += __shfl_xor(a1, 16); a1 += __shfl_xor(a1, 32);
    a2 += __shfl_xor(a2, 16); a2 += __shfl_xor(a2, 32);
    s1[tn] = a1; s2[tn] = a2;
  }
  if (hi4 == 0) {
#pragma unroll
    for (int tn = 0; tn < 4; ++tn) {
      ps[w][tn*16 + lo16]  = s1[tn];
      pss[w][tn*16 + lo16] = s2[tn];
    }
  }
  __syncthreads();
  if (t < 64) {
    atomicAdd(&stats[t],      ps[0][t]+ps[1][t]+ps[2][t]+ps[3][t]);
    atomicAdd(&stats[64 + t], pss[0][t]+pss[1][t]+pss[2][t]+pss[3][t]);
  }
}

// ---------------------------------------------------------------- MLP layers 2/3 via MFMA
template <int COUT>
__global__ __launch_bounds__(256) void k_layerM(const float* __restrict__ xin,
                                                const float* __restrict__ aff,
                                                const ushort_t* __restrict__ wp,
                                                float* __restrict__ y,
                                                float* __restrict__ stats) {
  const int r0 = blockIdx.x * 64;
  const int t = threadIdx.x;
  const int lane = t & 63;
  const int w = t >> 6;
  const int lo16 = lane & 15;
  const int hi4 = lane >> 4;
  constexpr int NTN = COUT >> 4;
  __shared__ __align__(16) ushort_t XbS[64*72];
  __shared__ float sa[64], sb[64];
  __shared__ float ps[4][COUT], pss[4][COUT];
  if (t < 64) { sa[t] = aff[t]; sb[t] = aff[64 + t]; }
  __syncthreads();
#pragma unroll
  for (int i = 0; i < 16; ++i) {
    int idx = t + 256*i;
    int r = idx >> 6, c = idx & 63;
    float v = xin[(size_t)r0*64 + idx];
    XbS[r*72 + c] = f2b(fmaxf(sa[c]*v + sb[c], 0.0f));
  }
  __syncthreads();
  const int arow = (w*16 + lo16)*72;
  float s1[NTN], s2[NTN];
#pragma unroll
  for (int tn = 0; tn < NTN; ++tn) {
    f32x4 acc = {0.f,0.f,0.f,0.f};
#pragma unroll
    for (int tk = 0; tk < 2; ++tk) {
      bf16x8 a = *(const bf16x8*)(XbS + arow + tk*32 + hi4*8);
      bf16x8 b = *(const bf16x8*)(wp + ((tk*NTN + tn) << 9) + (lane << 3));
      acc = MFMA(a, b, acc);
    }
    int col = tn*16 + lo16;
    int rbase = r0 + w*16 + hi4*4;
    float a1 = 0.f, a2 = 0.f;
#pragma unroll
    for (int r = 0; r < 4; ++r) {
      y[(size_t)(rbase + r)*COUT + col] = acc[r];
      a1 += acc[r]; a2 += acc[r]*acc[r];
    }
    a1 += __shfl_xor(a1, 16); a1 += __shfl_xor(a1, 32);
    a2 += __shfl_xor(a2, 16); a2 += __shfl_xor(a2, 32);
    s1[tn] = a1; s2[tn] = a2;
  }
  if (hi4 == 0) {
#pragma unroll
    for (int tn = 0; tn < NTN; ++tn) {
      ps[w][tn*16 + lo16]  = s1[tn];
      pss[w][tn*16 + lo16] = s2[tn];
    }
  }
  __syncthreads();
  if (t < COUT) {
    atomicAdd(&stats[t],        ps[0][t]+ps[1][t]+ps[2][t]+ps[3][t]);
    atomicAdd(&stats[COUT + t], pss[0][t]+pss[1][t]+pss[2][t]+pss[3][t]);
  }
}

// ---------------------------------------------------------------- BN stats -> affine
__global__ void k_finalize(const float* __restrict__ stats, const float* __restrict__ g,
                           const float* __restrict__ b, float* __restrict__ aff, int cout) {
  int t = threadIdx.x;
  if (t < cout) {
    const float inv = 1.0f / (float)NM;
    float m = stats[t] * inv;
    float var = stats[cout + t] * inv - m*m;
    float a = g[t] * rsqrtf(var + EPSF);
    aff[t] = a;
    aff[cout + t] = b[t] - m * a;
  }
}

// ---------------------------------------------------------------- pack weights (bf16 B-fragment layout)
__global__ __launch_bounds__(256) void k_pack(const float* __restrict__ ws,
                                              const float* __restrict__ wqkv,
                                              const float* __restrict__ wo,
                                              const float* __restrict__ w2,
                                              const float* __restrict__ w3,
                                              ushort_t* __restrict__ wpk) {
  int gid = blockIdx.x*256 + threadIdx.x;    // < 307200
  if (gid < 294912) {
    const float* src; int N_; int rem;
    if (gid < 163840)      { int mat = gid >> 14; rem = gid & 16383; src = ws  + (size_t)mat*16384; N_ = 128; }
    else if (gid < 262144) { int g2 = gid - 163840; int d = g2/49152; rem = g2 - d*49152; src = wqkv + (size_t)d*49152; N_ = 384; }
    else                   { int g3 = gid - 262144; int d = g3 >> 14; rem = g3 & 16383;  src = wo  + (size_t)d*16384; N_ = 128; }
    int NTN = N_ >> 4;
    int tile = rem >> 9, r = rem & 511;
    int tk = tile / NTN, tn = tile % NTN;
    int lane2 = r >> 3, jj = r & 7;
    int k = tk*32 + (lane2 >> 4)*8 + jj;
    int n = tn*16 + (lane2 & 15);
    wpk[gid] = f2b(src[(size_t)k*N_ + n]);
  } else if (gid < 299008) {
    int rem = gid - 294912;                  // w2: NTN=4, src[n*64+k]
    int tile = rem >> 9, r = rem & 511;
    int tk = tile >> 2, tn = tile & 3;
    int lane2 = r >> 3, jj = r & 7;
    int k = tk*32 + (lane2 >> 4)*8 + jj;
    int n = tn*16 + (lane2 & 15);
    wpk[gid] = f2b(w2[n*64 + k]);
  } else if (gid < 307200) {
    int rem = gid - 299008;                  // w3: NTN=8, src[n*64+k]
    int tile = rem >> 9, r = rem & 511;
    int tk = tile >> 3, tn = tile & 7;
    int lane2 = r >> 3, jj = r & 7;
    int k = tk*32 + (lane2 >> 4)*8 + jj;
    int n = tn*16 + (lane2 & 15);
    wpk[gid] = f2b(w3[n*64 + k]);
  }
}

// ---------------------------------------------------------------- fused per-group v4b
__global__ __launch_bounds__(256, 2) void k_group(
    const float* __restrict__ h3, const float* __restrict__ aff3,
    const float* __restrict__ gnorm,
    const ushort_t* __restrict__ wpk,
    const float* __restrict__ wb, const float* __restrict__ alpha,
    const float* __restrict__ ln1g, const float* __restrict__ ln1b,
    const float* __restrict__ ln2g, const float* __restrict__ ln2b,
    float* __restrict__ out) {
  const int p = blockIdx.x;
  const int t = threadIdx.x;
  const int lane = t & 63;
  const int w = t >> 6;
  const int lo16 = lane & 15;
  const int hi4 = lane >> 4;

  __shared__ __align__(16) ushort_t hbS[NK*NC];
  __shared__ __align__(16) ushort_t psisS[5*32*40];
  __shared__ __align__(16) unsigned char scratch[27648];

  float*    ddAF = (float*)scratch;
  float*    pxF  = (float*)(scratch + 4224);
  float*    dinvF= (float*)(scratch + 4608);
  float*    sigF = (float*)(scratch + 4736);
  ushort_t* LbS  = (ushort_t*)(scratch + 4768);
  ushort_t* PmS  = (ushort_t*)(scratch + 7328);
  ushort_t* qS   = (ushort_t*)scratch;
  ushort_t* kS2  = (ushort_t*)(scratch + 8704);
  ushort_t* vTS  = (ushort_t*)(scratch + 17408);
  float*    rowStat = (float*)(scratch + 20480);

  const int c0 = 32*w + lo16, c1 = c0 + 16;

  if (t < 96) pxF[t] = gnorm[(size_t)p*96 + t];
  const float* h3p = h3 + (size_t)p*4096;
#pragma unroll
  for (int i = 0; i < 16; ++i) {
    int idx = t + 256*i;
    int c = idx & 127, row = idx >> 7;
    float v = fmaxf(aff3[c]*h3p[idx] + aff3[128+c], 0.f);
    int ha = ((row << 8) + (c << 1)) ^ ((row & 7) << 4);
    hbS[ha >> 1] = f2b(v);
  }
  float hc[2][2][4];
  {
    float ga0 = aff3[c0], gb0 = aff3[128+c0];
    float ga1 = aff3[c1], gb1 = aff3[128+c1];
#pragma unroll
    for (int mi = 0; mi < 2; ++mi)
#pragma unroll
      for (int r = 0; r < 4; ++r) {
        int row = mi*16 + hi4*4 + r;
        hc[mi][0][r] = fmaxf(ga0*h3p[row*NC + c0] + gb0, 0.f);
        hc[mi][1][r] = fmaxf(ga1*h3p[row*NC + c1] + gb1, 0.f);
      }
  }
  __syncthreads();
  for (int i = t; i < 1024; i += 256) {
    int k = i >> 5, l = i & 31;
    float dx = pxF[k*3]  -pxF[l*3];
    float dy = pxF[k*3+1]-pxF[l*3+1];
    float dz = pxF[k*3+2]-pxF[l*3+2];
    ddAF[k*33+l] = dx*dx + dy*dy + dz*dz;
  }
  __syncthreads();
  float part = 0.f;
  for (int i = t; i < 1024; i += 256) part += sqrtf(ddAF[(i>>5)*33 + (i&31)] + 1e-12f);
#pragma unroll
  for (int off = 32; off; off >>= 1) part += __shfl_xor(part, off);
  if (lane == 0) sigF[w] = part;
  __syncthreads();
  if (t == 0) {
    float sg = (sigF[0]+sigF[1]+sigF[2]+sigF[3]) * (1.0f/1024.0f);
    sigF[4] = 2.0f*sg*sg + 1e-12f;
  }
  __syncthreads();
  const float denom = sigF[4];
  for (int i = t; i < 1024; i += 256) {
    int k = i >> 5, l = i & 31;
    ddAF[k*33+l] = expf(-ddAF[k*33+l] / denom);
  }
  __syncthreads();
  if (t < 32) {
    float s = 0.f;
    for (int l = 0; l < 32; ++l) s += ddAF[t*33 + l];
    dinvF[t] = rsqrtf(s + 1e-12f);
  }
  __syncthreads();
  for (int i = t; i < 1024; i += 256) {
    int k = i >> 5, l = i & 31;
    float v = -(dinvF[k] * ddAF[k*33+l] * dinvF[l]);
    if (k == l) v += 1.0f;
    LbS[k*40+l] = f2b(v);
  }
  __syncthreads();
  {
    int mi2 = w >> 1, ni2 = w & 1;
    int arow = (mi2*16 + lo16)*80 + (hi4 << 4);
    int brow = (ni2*16 + lo16)*80 + (hi4 << 4);
    bf16x8 bfr = *(const bf16x8*)((const char*)LbS + brow);
#pragma unroll
    for (int m = 2; m <= 4; ++m) {
      const ushort_t* Asrc = (m == 2) ? LbS : (PmS + (m-3)*1280);
      bf16x8 afr = *(const bf16x8*)((const char*)Asrc + arow);
      f32x4 z = {0.f,0.f,0.f,0.f};
      f32x4 pv = MFMA(afr, bfr, z);
      int rb2 = mi2*16 + hi4*4;
      int cl = ni2*16 + lo16;
#pragma unroll
      for (int r = 0; r < 4; ++r) PmS[(m-2)*1280 + (rb2+r)*40 + cl] = f2b(pv[r]);
      __syncthreads();
    }
  }
  for (int i = t; i < 1024; i += 256) {
    int k = i >> 5, l = i & 31;
    float lb = b2f(LbS[k*40+l]);
    float p2 = b2f(PmS[k*40+l]);
    float p3 = b2f(PmS[1280 + k*40+l]);
    float p4 = b2f(PmS[2560 + k*40+l]);
    float diag = (k == l) ? 1.0f : 0.0f;
#pragma unroll
    for (int j = 0; j < NJ; ++j) {
      float sj = -0.05f * (float)(1 << j);
      float cc2 = 0.5f*sj*sj;
      float cc3 = cc2*sj*(1.0f/3.0f);
      float cc4 = cc3*sj*0.25f;
      psisS[j*1280 + k*40 + l] = f2b(diag + sj*lb + cc2*p2 + cc3*p3 + cc4*p4);
    }
  }

  for (int d = 0; d < NDEPTH; ++d) {
    f32x4 m00 = {0.f,0.f,0.f,0.f}, m01 = m00, m10 = m00, m11 = m00;
    for (int jp = 0; jp < 3; ++jp) {
      const int njp = (jp == 2) ? 1 : 2;
      __syncthreads();
      for (int jj = 0; jj < njp; ++jj) {
        int j = 2*jp + jj;
        ushort_t* HjS = (ushort_t*)scratch + jj*5120;
        const ushort_t* Wp = wpk + (size_t)(d*NJ + j)*16384;
        const float alj = alpha[d*NJ + j];
#pragma unroll
        for (int tni = 0; tni < 2; ++tni) {
          int tn = 2*w + tni;
          f32x4 acc0 = {0.f,0.f,0.f,0.f}, acc1 = acc0;
#pragma unroll
          for (int tk = 0; tk < 4; ++tk) {
            bf16x8 bfr = *(const bf16x8*)(Wp + ((tk*8 + tn) << 9) + (lane << 3));
            int row0 = lo16;
            int ba0 = ((row0 << 8) + (tk << 6) + (hi4 << 4)) ^ ((row0 & 7) << 4);
            bf16x8 a0 = *(const bf16x8*)((const char*)hbS + ba0);
            acc0 = MFMA(a0, bfr, acc0);
            int row1 = 16 + lo16;
            int ba1 = ((row1 << 8) + (tk << 6) + (hi4 << 4)) ^ ((row1 & 7) << 4);
            bf16x8 a1 = *(const bf16x8*)((const char*)hbS + ba1);
            acc1 = MFMA(a1, bfr, acc1);
          }
          int c = tn*16 + lo16;
          int rbase = hi4*4;
#pragma unroll
          for (int r = 0; r < 4; ++r) {
            HjS[c*40 + rbase + r]      = f2b(alj * acc0[r]);
            HjS[c*40 + 16 + rbase + r] = f2b(alj * acc1[r]);
          }
        }
      }
      __syncthreads();
      for (int jj = 0; jj < njp; ++jj) {
        int j = 2*jp + jj;
        const char* psj = (const char*)(psisS + j*1280);
        const char* HjB = (const char*)scratch + jj*10240;
        int koff = hi4 << 4;
        bf16x8 pa0 = *(const bf16x8*)(psj + lo16*80 + koff);
        bf16x8 pa1 = *(const bf16x8*)(psj + (16 + lo16)*80 + koff);
        bf16x8 hb0 = *(const bf16x8*)(HjB + c0*80 + koff);
        bf16x8 hb1 = *(const bf16x8*)(HjB + c1*80 + koff);
        m00 = MFMA(pa0, hb0, m00);
        m01 = MFMA(pa0, hb1, m01);
        m10 = MFMA(pa1, hb0, m10);
        m11 = MFMA(pa1, hb1, m11);
      }
    }
    float u[2][2][4];
    {
      float wb0 = wb[d*NC + c0], wb1 = wb[d*NC + c1];
#pragma unroll
      for (int r = 0; r < 4; ++r) {
        u[0][0][r] = hc[0][0][r] + fmaxf(m00[r] + wb0, 0.f);
        u[0][1][r] = hc[0][1][r] + fmaxf(m01[r] + wb1, 0.f);
        u[1][0][r] = hc[1][0][r] + fmaxf(m10[r] + wb0, 0.f);
        u[1][1][r] = hc[1][1][r] + fmaxf(m11[r] + wb1, 0.f);
      }
#pragma unroll
      for (int mi = 0; mi < 2; ++mi)
#pragma unroll
        for (int r = 0; r < 4; ++r) {
          float s = u[mi][0][r] + u[mi][1][r];
          float q = u[mi][0][r]*u[mi][0][r] + u[mi][1][r]*u[mi][1][r];
          s = dpp_sum16(s);
          q = dpp_sum16(q);
          if (lo16 == 0) {
            int row = mi*16 + hi4*4 + r;
            rowStat[row*8 + w*2]     = s;
            rowStat[row*8 + w*2 + 1] = q;
          }
        }
    }
    __syncthreads();
    {
      float g0 = ln1g[d*NC + c0], b0 = ln1b[d*NC + c0];
      float g1 = ln1g[d*NC + c1], b1 = ln1b[d*NC + c1];
#pragma unroll
      for (int mi = 0; mi < 2; ++mi)
#pragma unroll
        for (int r = 0; r < 4; ++r) {
          int row = mi*16 + hi4*4 + r;
          f32x4 a = *(const f32x4*)(rowStat + row*8);
          f32x4 bq = *(const f32x4*)(rowStat + row*8 + 4);
          float mu = (a[0]+a[2]+bq[0]+bq[2]) * (1.0f/128.0f);
          float ex2 = (a[1]+a[3]+bq[1]+bq[3]) * (1.0f/128.0f);
          float rs = rsqrtf(ex2 - mu*mu + EPSF);
          float h0 = (u[mi][0][r] - mu)*rs*g0 + b0;
          float h1 = (u[mi][1][r] - mu)*rs*g1 + b1;
          hc[mi][0][r] = h0; hc[mi][1][r] = h1;
          int ha0 = ((row << 8) + (c0 << 1)) ^ ((row & 7) << 4);
          int ha1 = ((row << 8) + (c1 << 1)) ^ ((row & 7) << 4);
          hbS[ha0 >> 1] = f2b(h0);
          hbS[ha1 >> 1] = f2b(h1);
        }
    }
    __syncthreads();
    const ushort_t* Wq = wpk + 163840 + (size_t)d*49152;
#pragma unroll
    for (int ti = 0; ti < 12; ++ti) {
      int tile = w + 4*ti;
      int mi = (tile >= 24) ? 1 : 0;
      int tn = tile - 24*mi;
      int comp = tn >> 3;
      int cb = (tn & 7) * 16;
      f32x4 acc = {0.f,0.f,0.f,0.f};
#pragma unroll
      for (int tk = 0; tk < 4; ++tk) {
        bf16x8 bfr = *(const bf16x8*)(Wq + ((tk*24 + tn) << 9) + (lane << 3));
        int row = mi*16 + lo16;
        int ba = ((row << 8) + (tk << 6) + (hi4 << 4)) ^ ((row & 7) << 4);
        bf16x8 a = *(const bf16x8*)((const char*)hbS + ba);
        acc = MFMA(a, bfr, acc);
      }
      int cl = cb + lo16;
      int rb2 = mi*16 + hi4*4;
      if (comp == 0) {
#pragma unroll
        for (int r = 0; r < 4; ++r) qS[(rb2+r)*136 + cl] = f2b(acc[r]);
      } else if (comp == 1) {
#pragma unroll
        for (int r = 0; r < 4; ++r) kS2[(rb2+r)*136 + cl] = f2b(acc[r]);
      } else {
#pragma unroll
        for (int r = 0; r < 4; ++r) vTS[cl*40 + rb2 + r] = f2b(acc[r]);
      }
    }
    __syncthreads();
    float scr[2][2][4];
#pragma unroll
    for (int ti = 0; ti < 2; ++ti) {
      int pi = w + 4*ti;
      int h = pi >> 1, mi = pi & 1;
      int koff = h*64 + (hi4 << 4);
      bf16x8 qa = *(const bf16x8*)((const char*)qS + (mi*16 + lo16)*272 + koff);
#pragma unroll
      for (int ni = 0; ni < 2; ++ni) {
        bf16x8 kb = *(const bf16x8*)((const char*)kS2 + (ni*16 + lo16)*272 + koff);
        f32x4 z = {0.f,0.f,0.f,0.f};
        f32x4 sv = MFMA(qa, kb, z);
#pragma unroll
        for (int r = 0; r < 4; ++r) scr[ti][ni][r] = sv[r] * 0.17677669529663687f;
      }
    }
    __syncthreads();
#pragma unroll
    for (int ti = 0; ti < 2; ++ti) {
      int pi = w + 4*ti;
      int h = pi >> 1, mi = pi & 1;
#pragma unroll
      for (int r = 0; r < 4; ++r) {
        float s0 = scr[ti][0][r], s1 = scr[ti][1][r];
        float mx = dpp_max16(fmaxf(s0, s1));
        float e0 = expf(s0 - mx), e1 = expf(s1 - mx);
        float sum = dpp_sum16(e0 + e1);
        float iv = 1.0f / sum;
        int row = mi*16 + hi4*4 + r;
        qS[row*136 + h*32 + lo16]      = f2b(e0*iv);
        qS[row*136 + h*32 + 16 + lo16] = f2b(e1*iv);
      }
    }
    __syncthreads();
#pragma unroll
    for (int ti = 0; ti < 4; ++ti) {
      int tile = w + 4*ti;
      int h = tile >> 2, mi = (tile >> 1) & 1, ni = tile & 1;
      bf16x8 aa = *(const bf16x8*)((const char*)qS + (mi*16 + lo16)*272 + h*64 + (hi4 << 4));
      bf16x8 vb = *(const bf16x8*)((const char*)vTS + (h*32 + ni*16 + lo16)*80 + (hi4 << 4));
      f32x4 z = {0.f,0.f,0.f,0.f};
      f32x4 ov = MFMA(aa, vb, z);
      int col = h*32 + ni*16 + lo16;
      int rb2 = mi*16 + hi4*4;
#pragma unroll
      for (int r = 0; r < 4; ++r) {
        int row = rb2 + r;
        int ha = ((row << 8) + (col << 1)) ^ ((row & 7) << 4);
        hbS[ha >> 1] = f2b(ov[r]);
      }
    }
    __syncthreads();
    const ushort_t* Wop = wpk + 262144 + (size_t)d*16384;
#pragma unroll
    for (int tni = 0; tni < 2; ++tni) {
      int tn = 2*w + tni;
      f32x4 acc0 = {0.f,0.f,0.f,0.f}, acc1 = acc0;
#pragma unroll
      for (int tk = 0; tk < 4; ++tk) {
        bf16x8 bfr = *(const bf16x8*)(Wop + ((tk*8 + tn) << 9) + (lane << 3));
        int row0 = lo16;
        int ba0 = ((row0 << 8) + (tk << 6) + (hi4 << 4)) ^ ((row0 & 7) << 4);
        bf16x8 a0 = *(const bf16x8*)((const char*)hbS + ba0);
        acc0 = MFMA(a0, bfr, acc0);
        int row1 = 16 + lo16;
        int ba1 = ((row1 << 8) + (tk << 6) + (hi4 << 4)) ^ ((row1 & 7) << 4);
        bf16x8 a1 = *(const bf16x8*)((const char*)hbS + ba1);
        acc1 = MFMA(a1, bfr, acc1);
      }
#pragma unroll
      for (int r = 0; r < 4; ++r) {
        u[0][tni][r] = hc[0][tni][r] + acc0[r];
        u[1][tni][r] = hc[1][tni][r] + acc1[r];
      }
    }
#pragma unroll
    for (int mi = 0; mi < 2; ++mi)
#pragma unroll
      for (int r = 0; r < 4; ++r) {
        float s = u[mi][0][r] + u[mi][1][r];
        float q = u[mi][0][r]*u[mi][0][r] + u[mi][1][r]*u[mi][1][r];
        s = dpp_sum16(s);
        q = dpp_sum16(q);
        if (lo16 == 0) {
          int row = mi*16 + hi4*4 + r;
          rowStat[row*8 + w*2]     = s;
          rowStat[row*8 + w*2 + 1] = q;
        }
      }
    __syncthreads();
    {
      float g0 = ln2g[d*NC + c0], b0 = ln2b[d*NC + c0];
      float g1 = ln2g[d*NC + c1], b1 = ln2b[d*NC + c1];
#pragma unroll
      for (int mi = 0; mi < 2; ++mi)
#pragma unroll
        for (int r = 0; r < 4; ++r) {
          int row = mi*16 + hi4*4 + r;
          f32x4 a = *(const f32x4*)(rowStat + row*8);
          f32x4 bq = *(const f32x4*)(rowStat + row*8 + 4);
          float mu = (a[0]+a[2]+bq[0]+bq[2]) * (1.0f/128.0f);
          float ex2 = (a[1]+a[3]+bq[1]+bq[3]) * (1.0f/128.0f);
          float rs = rsqrtf(ex2 - mu*mu + EPSF);
          float h0 = (u[mi][0][r] - mu)*rs*g0 + b0;
          float h1 = (u[mi][1][r] - mu)*rs*g1 + b1;
          hc[mi][0][r] = h0; hc[mi][1][r] = h1;
          int ha0 = ((row << 8) + (c0 << 1)) ^ ((row & 7) << 4);
          int ha1 = ((row << 8) + (c1 << 1)) ^ ((row & 7) << 4);
          hbS[ha0 >> 1] = f2b(h0);
          hbS[ha1 >> 1] = f2b(h1);
        }
    }
  }
  {
    float v0 = hc[0][0][0], v1 = hc[0][1][0];
#pragma unroll
    for (int r = 1; r < 4; ++r) { v0 = fmaxf(v0, hc[0][0][r]); v1 = fmaxf(v1, hc[0][1][r]); }
#pragma unroll
    for (int r = 0; r < 4; ++r) { v0 = fmaxf(v0, hc[1][0][r]); v1 = fmaxf(v1, hc[1][1][r]); }
    v0 = fmaxf(v0, __shfl_xor(v0, 16)); v0 = fmaxf(v0, __shfl_xor(v0, 32));
    v1 = fmaxf(v1, __shfl_xor(v1, 16)); v1 = fmaxf(v1, __shfl_xor(v1, 32));
    if (hi4 == 0) {
      out[(size_t)p*NC + c0] = v0;
      out[(size_t)p*NC + c1] = v1;
    }
  }
}

// ---------------------------------------------------------------- launcher
extern "C" void kernel_launch(void* const* d_in, const int* in_sizes, int n_in,
                              void* d_out, int out_size, void* d_ws, size_t ws_size,
                              hipStream_t stream) {
  const float* xyz    = (const float*)d_in[0];
  const float* points = (const float*)d_in[1];
  const float* w1     = (const float*)d_in[2];
  const float* g1     = (const float*)d_in[3];
  const float* b1     = (const float*)d_in[4];
  const float* w2     = (const float*)d_in[5];
  const float* g2     = (const float*)d_in[6];
  const float* b2     = (const float*)d_in[7];
  const float* w3     = (const float*)d_in[8];
  const float* g3     = (const float*)d_in[9];
  const float* b3     = (const float*)d_in[10];
  const float* wsW    = (const float*)d_in[11];
  const float* wb     = (const float*)d_in[12];
  const float* alpha  = (const float*)d_in[13];
  const float* wqkv   = (const float*)d_in[14];
  const float* wo     = (const float*)d_in[15];
  const float* ln1g   = (const float*)d_in[16];
  const float* ln1b   = (const float*)d_in[17];
  const float* ln2g   = (const float*)d_in[18];
  const float* ln2b   = (const float*)d_in[19];
  float* outp = (float*)d_out;

  float* wsf   = (float*)d_ws;
  float* gnorm = wsf;                        // 786432 f
  float* stats = wsf + 786432;               // 768 f
  float* aff   = wsf + 787200;               // 768 f
  int*   knn   = (int*)(wsf + 787968);       // 262144 i (reused as wpk after k_layer1M)
  ushort_t* wpk = (ushort_t*)(wsf + 787968); // 307200 bf16 (fits knn's 1 MB)
  float* h2    = wsf + 1050112;              // 16777216 f
  float* hX    = wsf + 17827328;             // 33554432 f (h1 first half, h3 full)
  // w1 B-frags live in hX's UNUSED second half until layerM<128> overwrites it
  ushort_t* wp1 = (ushort_t*)(wsf + 17827328 + 16777216);  // 6144 bf16

  hipMemsetAsync(stats, 0, 768*sizeof(float), stream);
  k_fps<<<NB, 256, 0, stream>>>(xyz, outp);
  k_knn<<<NPTS, 64, 0, stream>>>(xyz, outp, knn, gnorm);
  k_pack1<<<24, 256, 0, stream>>>(w1, wp1);
  k_layer1M<<<NM/64, 256, 0, stream>>>(points, knn, gnorm, wp1, hX, stats);
  k_pack<<<307200/256, 256, 0, stream>>>(wsW, wqkv, wo, w2, w3, wpk);
  k_finalize<<<1, 128, 0, stream>>>(stats, g1, b1, aff, 64);
  k_layerM<64><<<NM/64, 256, 0, stream>>>(hX, aff, wpk + 294912, h2, stats + 256);
  k_finalize<<<1, 128, 0, stream>>>(stats + 256, g2, b2, aff + 256, 64);
  k_layerM<128><<<NM/64, 256, 0, stream>>>(h2, aff + 256, wpk + 299008, hX, stats + 512);
  k_finalize<<<1, 128, 0, stream>>>(stats + 512, g3, b3, aff + 512, 128);
  k_group<<<NPTS, 256, 0, stream>>>(hX, aff + 512, gnorm, wpk, wb, alpha,
                                    ln1g, ln1b, ln2g, ln2b, outp + (size_t)NB*NS*3);
}

// Round 12
// 1699.472 us; speedup vs baseline: 1.2475x; 1.0335x over previous
//
#include <hip/hip_runtime.h>
#include <math.h>

#define NB 8
#define NP 4096
#define NCIN 64
#define NS 1024
#define NK 32
#define NC 128
#define NJ 5
#define NDEPTH 2
#define NH 4
#define NPTS (NB*NS)       /* 8192 groups */
#define NM (NPTS*NK)       /* 262144 rows */
#define EPSF 1e-5f

typedef float f32x4 __attribute__((ext_vector_type(4)));
typedef short bf16x8 __attribute__((ext_vector_type(8)));
typedef unsigned short ushort_t;
typedef unsigned long long u64;

#define MFMA(a,b,c) __builtin_amdgcn_mfma_f32_16x16x32_bf16(a,b,c,0,0,0)

__device__ __forceinline__ ushort_t f2b(float f) {
  unsigned int u = __float_as_uint(f);
  u = (u + 0x7fffu + ((u >> 16) & 1u)) >> 16;
  return (ushort_t)u;
}
__device__ __forceinline__ float b2f(ushort_t h) {
  unsigned int u = ((unsigned int)h) << 16;
  return __uint_as_float(u);
}

// DPP in-row-of-16 reduce (VALU pipe).
template<int CTRL>
__device__ __forceinline__ float dpp_f(float v) {
  return __int_as_float(__builtin_amdgcn_update_dpp(0, __float_as_int(v), CTRL, 0xf, 0xf, true));
}
__device__ __forceinline__ float dpp_sum16(float v) {
  v += dpp_f<0xB1>(v); v += dpp_f<0x4E>(v);
  v += dpp_f<0x141>(v); v += dpp_f<0x140>(v);
  return v;
}
__device__ __forceinline__ float dpp_max16(float v) {
  v = fmaxf(v, dpp_f<0xB1>(v)); v = fmaxf(v, dpp_f<0x4E>(v));
  v = fmaxf(v, dpp_f<0x141>(v)); v = fmaxf(v, dpp_f<0x140>(v));
  return v;
}

#define DPPMAX(CTRL) { \
  unsigned lo2 = (unsigned)__builtin_amdgcn_update_dpp(0, (int)(unsigned)best, CTRL, 0xf, 0xf, true); \
  unsigned hi2 = (unsigned)__builtin_amdgcn_update_dpp(0, (int)(unsigned)(best >> 32), CTRL, 0xf, 0xf, true); \
  u64 o = ((u64)hi2 << 32) | lo2; \
  if (o > best) best = o; }

// min-reduce: invalid lanes keep OLD value (identity for min)
#define DPPMIN(CTRL) { \
  unsigned lo2 = (unsigned)__builtin_amdgcn_update_dpp((int)(unsigned)best, (int)(unsigned)best, CTRL, 0xf, 0xf, false); \
  unsigned hi2 = (unsigned)__builtin_amdgcn_update_dpp((int)(unsigned)(best >> 32), (int)(unsigned)(best >> 32), CTRL, 0xf, 0xf, false); \
  u64 o = ((u64)hi2 << 32) | lo2; \
  if (o < best) best = o; }

// ---------------------------------------------------------------- FPS (blocks 0..7) + w1 pack (blocks 8..31)
__global__ __launch_bounds__(256) void k_fps(const float* __restrict__ xyz,
                                             float* __restrict__ newxyz,
                                             const float* __restrict__ w1,
                                             ushort_t* __restrict__ wp1) {
  const int b = blockIdx.x;
  const int t = threadIdx.x;
  if (b >= NB) {
    // ---- w1 B-fragment pack: K=67 zero-padded to 96, N=64 (src [out][in])
    int gid = (b - NB)*256 + t;              // < 6144 (12 tiles x 512)
    int tile = gid >> 9, r = gid & 511;
    int tk = tile >> 2, tn = tile & 3;
    int lane2 = r >> 3, jj = r & 7;
    int k = tk*32 + (lane2 >> 4)*8 + jj;
    int n = tn*16 + (lane2 & 15);
    float v = (k < 67) ? w1[n*67 + k] : 0.0f;
    wp1[gid] = f2b(v);
    return;
  }
  const int lane = t & 63;
  const int w = t >> 6;
  __shared__ float Xl[NP*3];
  __shared__ float cenL[NS*3];
  __shared__ u64 slotP[2][4];
  __shared__ __align__(16) float slotC[2][4][4];
  const float* X = xyz + (size_t)b * NP * 3;
  for (int i = t; i < NP*3; i += 256) Xl[i] = X[i];
  __syncthreads();
  float px[16], py[16], pz[16], dist[16];
  unsigned inv[16];
#pragma unroll
  for (int i = 0; i < 16; ++i) {
    int n = t + 256*i;
    px[i] = Xl[3*n]; py[i] = Xl[3*n+1]; pz[i] = Xl[3*n+2];
    dist[i] = 1e10f;
    inv[i] = ~(unsigned)n;
  }
  float cx = Xl[0], cy = Xl[1], cz = Xl[2];
  for (int s = 0; s < NS; ++s) {
    if (t == 0) { cenL[3*s] = cx; cenL[3*s+1] = cy; cenL[3*s+2] = cz; }
    // inline u64 argmax tracking (dist >= 0 so raw-bit order OK; ascending n
    // with strict > keeps lowest index on ties; init 0 < any pack)
    u64 best = 0;
#pragma unroll
    for (int i = 0; i < 16; ++i) {
      float dx = px[i]-cx, dy = py[i]-cy, dz = pz[i]-cz;
      float d = fmaf(dx,dx, fmaf(dy,dy, dz*dz));
      float nd = fminf(dist[i], d);
      dist[i] = nd;
      u64 p = ((u64)__float_as_uint(nd) << 32) | inv[i];
      best = p > best ? p : best;
    }
    DPPMAX(0x111)
    DPPMAX(0x112)
    DPPMAX(0x114)
    DPPMAX(0x118)
    DPPMAX(0x142)
    DPPMAX(0x143)
    if (lane == 63) {
      slotP[s&1][w] = best;
      int bi3 = 3 * (int)(~(unsigned)best);
      slotC[s&1][w][0] = Xl[bi3];
      slotC[s&1][w][1] = Xl[bi3+1];
      slotC[s&1][w][2] = Xl[bi3+2];
    }
    __syncthreads();
    const int par = s & 1;
    u64 s0 = slotP[par][0], s1 = slotP[par][1], s2 = slotP[par][2], s3 = slotP[par][3];
    f32x4 c0v = *(const f32x4*)&slotC[par][0][0];
    f32x4 c1v = *(const f32x4*)&slotC[par][1][0];
    f32x4 c2v = *(const f32x4*)&slotC[par][2][0];
    f32x4 c3v = *(const f32x4*)&slotC[par][3][0];
    u64 m = s0; f32x4 cw = c0v;
    if (s1 > m) { m = s1; cw = c1v; }
    if (s2 > m) { m = s2; cw = c2v; }
    if (s3 > m) { m = s3; cw = c3v; }
    cx = cw[0]; cy = cw[1]; cz = cw[2];
  }
  __syncthreads();
  float* o = newxyz + (size_t)b * NS * 3;
  for (int i = t; i < NS*3; i += 256) o[i] = cenL[i];
}

// ---------------------------------------------------------------- KNN (DPP min-reduce, order-preserving key)
__global__ __launch_bounds__(64) void k_knn(const float* __restrict__ xyz,
                                            const float* __restrict__ newxyz,
                                            int* __restrict__ knn_idx,
                                            float* __restrict__ gnorm) {
  const int p = blockIdx.x;
  const int b = p >> 10;
  const int lane = threadIdx.x;
  const float* X = xyz + (size_t)b * NP * 3;
  __shared__ float d2[NP];
  float cx = newxyz[3*p], cy = newxyz[3*p+1], cz = newxyz[3*p+2];
  float sc = cx*cx + cy*cy + cz*cz;
#pragma unroll 4
  for (int i = 0; i < NP/64; ++i) {
    int n = lane + 64*i;
    float x = X[3*n], y = X[3*n+1], z = X[3*n+2];
    float sx = x*x + y*y + z*z;
    float dot = cx*x + cy*y + cz*z;
    d2[n] = sc + sx - 2.0f*dot;
  }
  for (int it = 0; it < NK; ++it) {
    float bv = 3.0e38f; int bi = 0x7fffffff;
#pragma unroll 8
    for (int i = 0; i < NP/64; ++i) {
      int n = lane + 64*i;
      float v = d2[n];
      if (v < bv) { bv = v; bi = n; }
    }
    unsigned ub = __float_as_uint(bv);
    ub ^= ((unsigned)((int)ub >> 31)) | 0x80000000u;   // float order -> unsigned order
    u64 best = ((u64)ub << 32) | (unsigned)bi;
    DPPMIN(0x111)
    DPPMIN(0x112)
    DPPMIN(0x114)
    DPPMIN(0x118)
    DPPMIN(0x142)
    DPPMIN(0x143)
    u64 win = __shfl(best, 63);
    if (lane == 0) {
      int wi = (int)(unsigned)win;
      d2[wi] = 3.3e38f;
      knn_idx[p*NK + it] = wi;
      float* g = gnorm + ((size_t)p*NK + it)*3;
      g[0] = X[3*wi]   - cx;
      g[1] = X[3*wi+1] - cy;
      g[2] = X[3*wi+2] - cz;
    }
  }
}

// ---------------------------------------------------------------- MLP layer 1 via MFMA
__global__ __launch_bounds__(256) void k_layer1M(const float* __restrict__ points,
                                                 const int* __restrict__ knn_idx,
                                                 const float* __restrict__ gnorm,
                                                 const ushort_t* __restrict__ wp1,
                                                 float* __restrict__ y,
                                                 float* __restrict__ stats) {
  const int r0 = blockIdx.x * 64;
  const int t = threadIdx.x;
  const int lane = t & 63;
  const int w = t >> 6;
  const int lo16 = lane & 15;
  const int hi4 = lane >> 4;
  __shared__ __align__(16) ushort_t XbS[64*104];
  __shared__ int nid[64];
  __shared__ float ps[4][64], pss[4][64];
  if (t < 64) nid[t] = knn_idx[r0 + t];
  __syncthreads();
  for (int idx = t; idx < 64*67; idx += 256) {
    int r = idx / 67, c = idx % 67;
    int row = r0 + r;
    float v;
    if (c < 3) v = gnorm[(size_t)row*3 + c];
    else {
      int bb = row >> 15;
      int n = nid[r];
      v = points[((size_t)bb*NP + n)*NCIN + (c-3)];
    }
    XbS[r*104 + c] = f2b(v);
  }
  for (int idx = t; idx < 64*37; idx += 256) {
    int r = idx / 37, c = idx % 37;
    XbS[r*104 + 67 + c] = 0;
  }
  __syncthreads();
  const int arow = (w*16 + lo16)*104;
  float s1[4], s2[4];
#pragma unroll
  for (int tn = 0; tn < 4; ++tn) {
    f32x4 acc = {0.f,0.f,0.f,0.f};
#pragma unroll
    for (int tk = 0; tk < 3; ++tk) {
      bf16x8 a = *(const bf16x8*)(XbS + arow + tk*32 + hi4*8);
      bf16x8 b = *(const bf16x8*)(wp1 + ((tk*4 + tn) << 9) + (lane << 3));
      acc = MFMA(a, b, acc);
    }
    int col = tn*16 + lo16;
    int rbase = r0 + w*16 + hi4*4;
    float a1 = 0.f, a2 = 0.f;
#pragma unroll
    for (int r = 0; r < 4; ++r) {
      y[(size_t)(rbase + r)*64 + col] = acc[r];
      a1 += acc[r]; a2 += acc[r]*acc[r];
    }
    a1 += __shfl_xor(a1, 16); a1 += __shfl_xor(a1, 32);
    a2 += __shfl_xor(a2, 16); a2 += __shfl_xor(a2, 32);
    s1[tn] = a1; s2[tn] = a2;
  }
  if (hi4 == 0) {
#pragma unroll
    for (int tn = 0; tn < 4; ++tn) {
      ps[w][tn*16 + lo16]  = s1[tn];
      pss[w][tn*16 + lo16] = s2[tn];
    }
  }
  __syncthreads();
  if (t < 64) {
    atomicAdd(&stats[t],      ps[0][t]+ps[1][t]+ps[2][t]+ps[3][t]);
    atomicAdd(&stats[64 + t], pss[0][t]+pss[1][t]+pss[2][t]+pss[3][t]);
  }
}

// ---------------------------------------------------------------- MLP layers 2/3 via MFMA (affine computed in-block)
template <int COUT>
__global__ __launch_bounds__(256) void k_layerM(const float* __restrict__ xin,
                                                const float* __restrict__ stats_in,
                                                const float* __restrict__ g,
                                                const float* __restrict__ bb_,
                                                const ushort_t* __restrict__ wp,
                                                float* __restrict__ y,
                                                float* __restrict__ stats) {
  const int r0 = blockIdx.x * 64;
  const int t = threadIdx.x;
  const int lane = t & 63;
  const int w = t >> 6;
  const int lo16 = lane & 15;
  const int hi4 = lane >> 4;
  constexpr int NTN = COUT >> 4;
  __shared__ __align__(16) ushort_t XbS[64*72];
  __shared__ float sa[64], sb[64];
  __shared__ float ps[4][COUT], pss[4][COUT];
  if (t < 64) {
    const float inv = 1.0f / (float)NM;
    float m = stats_in[t] * inv;
    float var = stats_in[64 + t] * inv - m*m;
    float a = g[t] * rsqrtf(var + EPSF);
    sa[t] = a;
    sb[t] = bb_[t] - m * a;
  }
  __syncthreads();
#pragma unroll
  for (int i = 0; i < 16; ++i) {
    int idx = t + 256*i;
    int r = idx >> 6, c = idx & 63;
    float v = xin[(size_t)r0*64 + idx];
    XbS[r*72 + c] = f2b(fmaxf(sa[c]*v + sb[c], 0.0f));
  }
  __syncthreads();
  const int arow = (w*16 + lo16)*72;
  float s1[NTN], s2[NTN];
#pragma unroll
  for (int tn = 0; tn < NTN; ++tn) {
    f32x4 acc = {0.f,0.f,0.f,0.f};
#pragma unroll
    for (int tk = 0; tk < 2; ++tk) {
      bf16x8 a = *(const bf16x8*)(XbS + arow + tk*32 + hi4*8);
      bf16x8 b = *(const bf16x8*)(wp + ((tk*NTN + tn) << 9) + (lane << 3));
      acc = MFMA(a, b, acc);
    }
    int col = tn*16 + lo16;
    int rbase = r0 + w*16 + hi4*4;
    float a1 = 0.f, a2 = 0.f;
#pragma unroll
    for (int r = 0; r < 4; ++r) {
      y[(size_t)(rbase + r)*COUT + col] = acc[r];
      a1 += acc[r]; a2 += acc[r]*acc[r];
    }
    a1 += __shfl_xor(a1, 16); a1 += __shfl_xor(a1, 32);
    a2 += __shfl_xor(a2, 16); a2 += __shfl_xor(a2, 32);
    s1[tn] = a1; s2[tn] = a2;
  }
  if (hi4 == 0) {
#pragma unroll
    for (int tn = 0; tn < NTN; ++tn) {
      ps[w][tn*16 + lo16]  = s1[tn];
      pss[w][tn*16 + lo16] = s2[tn];
    }
  }
  __syncthreads();
  if (t < COUT) {
    atomicAdd(&stats[t],        ps[0][t]+ps[1][t]+ps[2][t]+ps[3][t]);
    atomicAdd(&stats[COUT + t], pss[0][t]+pss[1][t]+pss[2][t]+pss[3][t]);
  }
}

// ---------------------------------------------------------------- pack weights (bf16 B-fragment layout)
__global__ __launch_bounds__(256) void k_pack(const float* __restrict__ ws,
                                              const float* __restrict__ wqkv,
                                              const float* __restrict__ wo,
                                              const float* __restrict__ w2,
                                              const float* __restrict__ w3,
                                              ushort_t* __restrict__ wpk) {
  int gid = blockIdx.x*256 + threadIdx.x;    // < 307200
  if (gid < 294912) {
    const float* src; int N_; int rem;
    if (gid < 163840)      { int mat = gid >> 14; rem = gid & 16383; src = ws  + (size_t)mat*16384; N_ = 128; }
    else if (gid < 262144) { int g2 = gid - 163840; int d = g2/49152; rem = g2 - d*49152; src = wqkv + (size_t)d*49152; N_ = 384; }
    else                   { int g3 = gid - 262144; int d = g3 >> 14; rem = g3 & 16383;  src = wo  + (size_t)d*16384; N_ = 128; }
    int NTN = N_ >> 4;
    int tile = rem >> 9, r = rem & 511;
    int tk = tile / NTN, tn = tile % NTN;
    int lane2 = r >> 3, jj = r & 7;
    int k = tk*32 + (lane2 >> 4)*8 + jj;
    int n = tn*16 + (lane2 & 15);
    wpk[gid] = f2b(src[(size_t)k*N_ + n]);
  } else if (gid < 299008) {
    int rem = gid - 294912;                  // w2: NTN=4, src[n*64+k]
    int tile = rem >> 9, r = rem & 511;
    int tk = tile >> 2, tn = tile & 3;
    int lane2 = r >> 3, jj = r & 7;
    int k = tk*32 + (lane2 >> 4)*8 + jj;
    int n = tn*16 + (lane2 & 15);
    wpk[gid] = f2b(w2[n*64 + k]);
  } else if (gid < 307200) {
    int rem = gid - 299008;                  // w3: NTN=8, src[n*64+k]
    int tile = rem >> 9, r = rem & 511;
    int tk = tile >> 3, tn = tile & 7;
    int lane2 = r >> 3, jj = r & 7;
    int k = tk*32 + (lane2 >> 4)*8 + jj;
    int n = tn*16 + (lane2 & 15);
    wpk[gid] = f2b(w3[n*64 + k]);
  }
}

// ---------------------------------------------------------------- fused per-group v4c (aff3 in-block; fused prologue)
__global__ __launch_bounds__(256, 2) void k_group(
    const float* __restrict__ h3,
    const float* __restrict__ stats3, const float* __restrict__ g3,
    const float* __restrict__ b3,
    const float* __restrict__ gnorm,
    const ushort_t* __restrict__ wpk,
    const float* __restrict__ wb, const float* __restrict__ alpha,
    const float* __restrict__ ln1g, const float* __restrict__ ln1b,
    const float* __restrict__ ln2g, const float* __restrict__ ln2b,
    float* __restrict__ out) {
  const int p = blockIdx.x;
  const int t = threadIdx.x;
  const int lane = t & 63;
  const int w = t >> 6;
  const int lo16 = lane & 15;
  const int hi4 = lane >> 4;

  __shared__ __align__(16) ushort_t hbS[NK*NC];
  __shared__ __align__(16) ushort_t psisS[5*32*40];
  __shared__ __align__(16) unsigned char scratch[27648];

  float*    ddAF = (float*)scratch;
  float*    pxF  = (float*)(scratch + 4224);
  float*    dinvF= (float*)(scratch + 4608);
  float*    sigF = (float*)(scratch + 4736);
  ushort_t* LbS  = (ushort_t*)(scratch + 4768);
  ushort_t* PmS  = (ushort_t*)(scratch + 7328);
  ushort_t* qS   = (ushort_t*)scratch;
  ushort_t* kS2  = (ushort_t*)(scratch + 8704);
  ushort_t* vTS  = (ushort_t*)(scratch + 17408);
  float*    rowStat = (float*)(scratch + 20480);
  float*    aff3S = rowStat;       // 256 floats; dead before LN1 uses rowStat

  const int c0 = 32*w + lo16, c1 = c0 + 16;

  // ---- aff3 from stats (replaces k_finalize)
  if (t < 128) {
    const float invn = 1.0f / (float)NM;
    float m = stats3[t] * invn;
    float var = stats3[128 + t] * invn - m*m;
    float a = g3[t] * rsqrtf(var + EPSF);
    aff3S[t] = a;
    aff3S[128 + t] = b3[t] - m * a;
  }
  if (t < 96) pxF[t] = gnorm[(size_t)p*96 + t];
  __syncthreads();
  const float* h3p = h3 + (size_t)p*4096;
#pragma unroll
  for (int i = 0; i < 16; ++i) {
    int idx = t + 256*i;
    int c = idx & 127, row = idx >> 7;
    float v = fmaxf(aff3S[c]*h3p[idx] + aff3S[128+c], 0.f);
    int ha = ((row << 8) + (c << 1)) ^ ((row & 7) << 4);
    hbS[ha >> 1] = f2b(v);
  }
  float hc[2][2][4];
  {
    float ga0 = aff3S[c0], gb0 = aff3S[128+c0];
    float ga1 = aff3S[c1], gb1 = aff3S[128+c1];
#pragma unroll
    for (int mi = 0; mi < 2; ++mi)
#pragma unroll
      for (int r = 0; r < 4; ++r) {
        int row = mi*16 + hi4*4 + r;
        hc[mi][0][r] = fmaxf(ga0*h3p[row*NC + c0] + gb0, 0.f);
        hc[mi][1][r] = fmaxf(ga1*h3p[row*NC + c1] + gb1, 0.f);
      }
  }
  __syncthreads();
  // ---- dd + sigma partial fused (one pass)
  float part = 0.f;
  for (int i = t; i < 1024; i += 256) {
    int k = i >> 5, l = i & 31;
    float dx = pxF[k*3]  -pxF[l*3];
    float dy = pxF[k*3+1]-pxF[l*3+1];
    float dz = pxF[k*3+2]-pxF[l*3+2];
    float dd = dx*dx + dy*dy + dz*dz;
    ddAF[k*33+l] = dd;
    part += sqrtf(dd + 1e-12f);
  }
#pragma unroll
  for (int off = 32; off; off >>= 1) part += __shfl_xor(part, off);
  if (lane == 0) sigF[w] = part;
  __syncthreads();
  if (t == 0) {
    float sg = (sigF[0]+sigF[1]+sigF[2]+sigF[3]) * (1.0f/1024.0f);
    sigF[4] = 2.0f*sg*sg + 1e-12f;
  }
  __syncthreads();
  const float denom = sigF[4];
  for (int i = t; i < 1024; i += 256) {
    int k = i >> 5, l = i & 31;
    ddAF[k*33+l] = expf(-ddAF[k*33+l] / denom);
  }
  __syncthreads();
  {  // dinv: 8 threads per row
    int row = t >> 3, e = t & 7;
    float s = ddAF[row*33 + e] + ddAF[row*33 + e + 8]
            + ddAF[row*33 + e + 16] + ddAF[row*33 + e + 24];
    s += __shfl_xor(s,1); s += __shfl_xor(s,2); s += __shfl_xor(s,4);
    if (e == 0) dinvF[row] = rsqrtf(s + 1e-12f);
  }
  __syncthreads();
  for (int i = t; i < 1024; i += 256) {
    int k = i >> 5, l = i & 31;
    float v = -(dinvF[k] * ddAF[k*33+l] * dinvF[l]);
    if (k == l) v += 1.0f;
    LbS[k*40+l] = f2b(v);
  }
  __syncthreads();
  {
    int mi2 = w >> 1, ni2 = w & 1;
    int arow = (mi2*16 + lo16)*80 + (hi4 << 4);
    int brow = (ni2*16 + lo16)*80 + (hi4 << 4);
    bf16x8 bfr = *(const bf16x8*)((const char*)LbS + brow);
#pragma unroll
    for (int m = 2; m <= 4; ++m) {
      const ushort_t* Asrc = (m == 2) ? LbS : (PmS + (m-3)*1280);
      bf16x8 afr = *(const bf16x8*)((const char*)Asrc + arow);
      f32x4 z = {0.f,0.f,0.f,0.f};
      f32x4 pv = MFMA(afr, bfr, z);
      int rb2 = mi2*16 + hi4*4;
      int cl = ni2*16 + lo16;
#pragma unroll
      for (int r = 0; r < 4; ++r) PmS[(m-2)*1280 + (rb2+r)*40 + cl] = f2b(pv[r]);
      __syncthreads();
    }
  }
  for (int i = t; i < 1024; i += 256) {
    int k = i >> 5, l = i & 31;
    float lb = b2f(LbS[k*40+l]);
    float p2 = b2f(PmS[k*40+l]);
    float p3 = b2f(PmS[1280 + k*40+l]);
    float p4 = b2f(PmS[2560 + k*40+l]);
    float diag = (k == l) ? 1.0f : 0.0f;
#pragma unroll
    for (int j = 0; j < NJ; ++j) {
      float sj = -0.05f * (float)(1 << j);
      float cc2 = 0.5f*sj*sj;
      float cc3 = cc2*sj*(1.0f/3.0f);
      float cc4 = cc3*sj*0.25f;
      psisS[j*1280 + k*40 + l] = f2b(diag + sj*lb + cc2*p2 + cc3*p3 + cc4*p4);
    }
  }

  for (int d = 0; d < NDEPTH; ++d) {
    f32x4 m00 = {0.f,0.f,0.f,0.f}, m01 = m00, m10 = m00, m11 = m00;
    for (int jp = 0; jp < 3; ++jp) {
      const int njp = (jp == 2) ? 1 : 2;
      __syncthreads();
      for (int jj = 0; jj < njp; ++jj) {
        int j = 2*jp + jj;
        ushort_t* HjS = (ushort_t*)scratch + jj*5120;
        const ushort_t* Wp = wpk + (size_t)(d*NJ + j)*16384;
        const float alj = alpha[d*NJ + j];
#pragma unroll
        for (int tni = 0; tni < 2; ++tni) {
          int tn = 2*w + tni;
          f32x4 acc0 = {0.f,0.f,0.f,0.f}, acc1 = acc0;
#pragma unroll
          for (int tk = 0; tk < 4; ++tk) {
            bf16x8 bfr = *(const bf16x8*)(Wp + ((tk*8 + tn) << 9) + (lane << 3));
            int row0 = lo16;
            int ba0 = ((row0 << 8) + (tk << 6) + (hi4 << 4)) ^ ((row0 & 7) << 4);
            bf16x8 a0 = *(const bf16x8*)((const char*)hbS + ba0);
            acc0 = MFMA(a0, bfr, acc0);
            int row1 = 16 + lo16;
            int ba1 = ((row1 << 8) + (tk << 6) + (hi4 << 4)) ^ ((row1 & 7) << 4);
            bf16x8 a1 = *(const bf16x8*)((const char*)hbS + ba1);
            acc1 = MFMA(a1, bfr, acc1);
          }
          int c = tn*16 + lo16;
          int rbase = hi4*4;
#pragma unroll
          for (int r = 0; r < 4; ++r) {
            HjS[c*40 + rbase + r]      = f2b(alj * acc0[r]);
            HjS[c*40 + 16 + rbase + r] = f2b(alj * acc1[r]);
          }
        }
      }
      __syncthreads();
      for (int jj = 0; jj < njp; ++jj) {
        int j = 2*jp + jj;
        const char* psj = (const char*)(psisS + j*1280);
        const char* HjB = (const char*)scratch + jj*10240;
        int koff = hi4 << 4;
        bf16x8 pa0 = *(const bf16x8*)(psj + lo16*80 + koff);
        bf16x8 pa1 = *(const bf16x8*)(psj + (16 + lo16)*80 + koff);
        bf16x8 hb0 = *(const bf16x8*)(HjB + c0*80 + koff);
        bf16x8 hb1 = *(const bf16x8*)(HjB + c1*80 + koff);
        m00 = MFMA(pa0, hb0, m00);
        m01 = MFMA(pa0, hb1, m01);
        m10 = MFMA(pa1, hb0, m10);
        m11 = MFMA(pa1, hb1, m11);
      }
    }
    float u[2][2][4];
    {
      float wb0 = wb[d*NC + c0], wb1 = wb[d*NC + c1];
#pragma unroll
      for (int r = 0; r < 4; ++r) {
        u[0][0][r] = hc[0][0][r] + fmaxf(m00[r] + wb0, 0.f);
        u[0][1][r] = hc[0][1][r] + fmaxf(m01[r] + wb1, 0.f);
        u[1][0][r] = hc[1][0][r] + fmaxf(m10[r] + wb0, 0.f);
        u[1][1][r] = hc[1][1][r] + fmaxf(m11[r] + wb1, 0.f);
      }
#pragma unroll
      for (int mi = 0; mi < 2; ++mi)
#pragma unroll
        for (int r = 0; r < 4; ++r) {
          float s = u[mi][0][r] + u[mi][1][r];
          float q = u[mi][0][r]*u[mi][0][r] + u[mi][1][r]*u[mi][1][r];
          s = dpp_sum16(s);
          q = dpp_sum16(q);
          if (lo16 == 0) {
            int row = mi*16 + hi4*4 + r;
            rowStat[row*8 + w*2]     = s;
            rowStat[row*8 + w*2 + 1] = q;
          }
        }
    }
    __syncthreads();
    {
      float g0 = ln1g[d*NC + c0], b0 = ln1b[d*NC + c0];
      float g1 = ln1g[d*NC + c1], b1 = ln1b[d*NC + c1];
#pragma unroll
      for (int mi = 0; mi < 2; ++mi)
#pragma unroll
        for (int r = 0; r < 4; ++r) {
          int row = mi*16 + hi4*4 + r;
          f32x4 a = *(const f32x4*)(rowStat + row*8);
          f32x4 bq = *(const f32x4*)(rowStat + row*8 + 4);
          float mu = (a[0]+a[2]+bq[0]+bq[2]) * (1.0f/128.0f);
          float ex2 = (a[1]+a[3]+bq[1]+bq[3]) * (1.0f/128.0f);
          float rs = rsqrtf(ex2 - mu*mu + EPSF);
          float h0 = (u[mi][0][r] - mu)*rs*g0 + b0;
          float h1 = (u[mi][1][r] - mu)*rs*g1 + b1;
          hc[mi][0][r] = h0; hc[mi][1][r] = h1;
          int ha0 = ((row << 8) + (c0 << 1)) ^ ((row & 7) << 4);
          int ha1 = ((row << 8) + (c1 << 1)) ^ ((row & 7) << 4);
          hbS[ha0 >> 1] = f2b(h0);
          hbS[ha1 >> 1] = f2b(h1);
        }
    }
    __syncthreads();
    const ushort_t* Wq = wpk + 163840 + (size_t)d*49152;
#pragma unroll
    for (int ti = 0; ti < 12; ++ti) {
      int tile = w + 4*ti;
      int mi = (tile >= 24) ? 1 : 0;
      int tn = tile - 24*mi;
      int comp = tn >> 3;
      int cb = (tn & 7) * 16;
      f32x4 acc = {0.f,0.f,0.f,0.f};
#pragma unroll
      for (int tk = 0; tk < 4; ++tk) {
        bf16x8 bfr = *(const bf16x8*)(Wq + ((tk*24 + tn) << 9) + (lane << 3));
        int row = mi*16 + lo16;
        int ba = ((row << 8) + (tk << 6) + (hi4 << 4)) ^ ((row & 7) << 4);
        bf16x8 a = *(const bf16x8*)((const char*)hbS + ba);
        acc = MFMA(a, bfr, acc);
      }
      int cl = cb + lo16;
      int rb2 = mi*16 + hi4*4;
      if (comp == 0) {
#pragma unroll
        for (int r = 0; r < 4; ++r) qS[(rb2+r)*136 + cl] = f2b(acc[r]);
      } else if (comp == 1) {
#pragma unroll
        for (int r = 0; r < 4; ++r) kS2[(rb2+r)*136 + cl] = f2b(acc[r]);
      } else {
#pragma unroll
        for (int r = 0; r < 4; ++r) vTS[cl*40 + rb2 + r] = f2b(acc[r]);
      }
    }
    __syncthreads();
    float scr[2][2][4];
#pragma unroll
    for (int ti = 0; ti < 2; ++ti) {
      int pi = w + 4*ti;
      int h = pi >> 1, mi = pi & 1;
      int koff = h*64 + (hi4 << 4);
      bf16x8 qa = *(const bf16x8*)((const char*)qS + (mi*16 + lo16)*272 + koff);
#pragma unroll
      for (int ni = 0; ni < 2; ++ni) {
        bf16x8 kb = *(const bf16x8*)((const char*)kS2 + (ni*16 + lo16)*272 + koff);
        f32x4 z = {0.f,0.f,0.f,0.f};
        f32x4 sv = MFMA(qa, kb, z);
#pragma unroll
        for (int r = 0; r < 4; ++r) scr[ti][ni][r] = sv[r] * 0.17677669529663687f;
      }
    }
    __syncthreads();
#pragma unroll
    for (int ti = 0; ti < 2; ++ti) {
      int pi = w + 4*ti;
      int h = pi >> 1, mi = pi & 1;
#pragma unroll
      for (int r = 0; r < 4; ++r) {
        float s0 = scr[ti][0][r], s1 = scr[ti][1][r];
        float mx = dpp_max16(fmaxf(s0, s1));
        float e0 = expf(s0 - mx), e1 = expf(s1 - mx);
        float sum = dpp_sum16(e0 + e1);
        float iv = 1.0f / sum;
        int row = mi*16 + hi4*4 + r;
        qS[row*136 + h*32 + lo16]      = f2b(e0*iv);
        qS[row*136 + h*32 + 16 + lo16] = f2b(e1*iv);
      }
    }
    __syncthreads();
#pragma unroll
    for (int ti = 0; ti < 4; ++ti) {
      int tile = w + 4*ti;
      int h = tile >> 2, mi = (tile >> 1) & 1, ni = tile & 1;
      bf16x8 aa = *(const bf16x8*)((const char*)qS + (mi*16 + lo16)*272 + h*64 + (hi4 << 4));
      bf16x8 vb = *(const bf16x8*)((const char*)vTS + (h*32 + ni*16 + lo16)*80 + (hi4 << 4));
      f32x4 z = {0.f,0.f,0.f,0.f};
      f32x4 ov = MFMA(aa, vb, z);
      int col = h*32 + ni*16 + lo16;
      int rb2 = mi*16 + hi4*4;
#pragma unroll
      for (int r = 0; r < 4; ++r) {
        int row = rb2 + r;
        int ha = ((row << 8) + (col << 1)) ^ ((row & 7) << 4);
        hbS[ha >> 1] = f2b(ov[r]);
      }
    }
    __syncthreads();
    const ushort_t* Wop = wpk + 262144 + (size_t)d*16384;
#pragma unroll
    for (int tni = 0; tni < 2; ++tni) {
      int tn = 2*w + tni;
      f32x4 acc0 = {0.f,0.f,0.f,0.f}, acc1 = acc0;
#pragma unroll
      for (int tk = 0; tk < 4; ++tk) {
        bf16x8 bfr = *(const bf16x8*)(Wop + ((tk*8 + tn) << 9) + (lane << 3));
        int row0 = lo16;
        int ba0 = ((row0 << 8) + (tk << 6) + (hi4 << 4)) ^ ((row0 & 7) << 4);
        bf16x8 a0 = *(const bf16x8*)((const char*)hbS + ba0);
        acc0 = MFMA(a0, bfr, acc0);
        int row1 = 16 + lo16;
        int ba1 = ((row1 << 8) + (tk << 6) + (hi4 << 4)) ^ ((row1 & 7) << 4);
        bf16x8 a1 = *(const bf16x8*)((const char*)hbS + ba1);
        acc1 = MFMA(a1, bfr, acc1);
      }
#pragma unroll
      for (int r = 0; r < 4; ++r) {
        u[0][tni][r] = hc[0][tni][r] + acc0[r];
        u[1][tni][r] = hc[1][tni][r] + acc1[r];
      }
    }
#pragma unroll
    for (int mi = 0; mi < 2; ++mi)
#pragma unroll
      for (int r = 0; r < 4; ++r) {
        float s = u[mi][0][r] + u[mi][1][r];
        float q = u[mi][0][r]*u[mi][0][r] + u[mi][1][r]*u[mi][1][r];
        s = dpp_sum16(s);
        q = dpp_sum16(q);
        if (lo16 == 0) {
          int row = mi*16 + hi4*4 + r;
          rowStat[row*8 + w*2]     = s;
          rowStat[row*8 + w*2 + 1] = q;
        }
      }
    __syncthreads();
    {
      float g0 = ln2g[d*NC + c0], b0 = ln2b[d*NC + c0];
      float g1 = ln2g[d*NC + c1], b1 = ln2b[d*NC + c1];
#pragma unroll
      for (int mi = 0; mi < 2; ++mi)
#pragma unroll
        for (int r = 0; r < 4; ++r) {
          int row = mi*16 + hi4*4 + r;
          f32x4 a = *(const f32x4*)(rowStat + row*8);
          f32x4 bq = *(const f32x4*)(rowStat + row*8 + 4);
          float mu = (a[0]+a[2]+bq[0]+bq[2]) * (1.0f/128.0f);
          float ex2 = (a[1]+a[3]+bq[1]+bq[3]) * (1.0f/128.0f);
          float rs = rsqrtf(ex2 - mu*mu + EPSF);
          float h0 = (u[mi][0][r] - mu)*rs*g0 + b0;
          float h1 = (u[mi][1][r] - mu)*rs*g1 + b1;
          hc[mi][0][r] = h0; hc[mi][1][r] = h1;
          int ha0 = ((row << 8) + (c0 << 1)) ^ ((row & 7) << 4);
          int ha1 = ((row << 8) + (c1 << 1)) ^ ((row & 7) << 4);
          hbS[ha0 >> 1] = f2b(h0);
          hbS[ha1 >> 1] = f2b(h1);
        }
    }
  }
  {
    float v0 = hc[0][0][0], v1 = hc[0][1][0];
#pragma unroll
    for (int r = 1; r < 4; ++r) { v0 = fmaxf(v0, hc[0][0][r]); v1 = fmaxf(v1, hc[0][1][r]); }
#pragma unroll
    for (int r = 0; r < 4; ++r) { v0 = fmaxf(v0, hc[1][0][r]); v1 = fmaxf(v1, hc[1][1][r]); }
    v0 = fmaxf(v0, __shfl_xor(v0, 16)); v0 = fmaxf(v0, __shfl_xor(v0, 32));
    v1 = fmaxf(v1, __shfl_xor(v1, 16)); v1 = fmaxf(v1, __shfl_xor(v1, 32));
    if (hi4 == 0) {
      out[(size_t)p*NC + c0] = v0;
      out[(size_t)p*NC + c1] = v1;
    }
  }
}

// ---------------------------------------------------------------- launcher
extern "C" void kernel_launch(void* const* d_in, const int* in_sizes, int n_in,
                              void* d_out, int out_size, void* d_ws, size_t ws_size,
                              hipStream_t stream) {
  const float* xyz    = (const float*)d_in[0];
  const float* points = (const float*)d_in[1];
  const float* w1     = (const float*)d_in[2];
  const float* g1     = (const float*)d_in[3];
  const float* b1     = (const float*)d_in[4];
  const float* w2     = (const float*)d_in[5];
  const float* g2     = (const float*)d_in[6];
  const float* b2     = (const float*)d_in[7];
  const float* w3     = (const float*)d_in[8];
  const float* g3     = (const float*)d_in[9];
  const float* b3     = (const float*)d_in[10];
  const float* wsW    = (const float*)d_in[11];
  const float* wb     = (const float*)d_in[12];
  const float* alpha  = (const float*)d_in[13];
  const float* wqkv   = (const float*)d_in[14];
  const float* wo     = (const float*)d_in[15];
  const float* ln1g   = (const float*)d_in[16];
  const float* ln1b   = (const float*)d_in[17];
  const float* ln2g   = (const float*)d_in[18];
  const float* ln2b   = (const float*)d_in[19];
  float* outp = (float*)d_out;

  float* wsf   = (float*)d_ws;
  float* gnorm = wsf;                        // 786432 f
  float* stats = wsf + 786432;               // 768 f
  int*   knn   = (int*)(wsf + 787968);       // 262144 i (reused as wpk after k_layer1M)
  ushort_t* wpk = (ushort_t*)(wsf + 787968); // 307200 bf16 (fits knn's 1 MB)
  float* h2    = wsf + 1050112;              // 16777216 f
  float* hX    = wsf + 17827328;             // 33554432 f (h1 first half, h3 full)
  ushort_t* wp1 = (ushort_t*)(wsf + 17827328 + 16777216);  // 6144 bf16 in hX tail

  hipMemsetAsync(stats, 0, 768*sizeof(float), stream);
  k_fps<<<NB + 24, 256, 0, stream>>>(xyz, outp, w1, wp1);
  k_knn<<<NPTS, 64, 0, stream>>>(xyz, outp, knn, gnorm);
  k_layer1M<<<NM/64, 256, 0, stream>>>(points, knn, gnorm, wp1, hX, stats);
  k_pack<<<307200/256, 256, 0, stream>>>(wsW, wqkv, wo, w2, w3, wpk);
  k_layerM<64><<<NM/64, 256, 0, stream>>>(hX, stats, g1, b1, wpk + 294912, h2, stats + 256);
  k_layerM<128><<<NM/64, 256, 0, stream>>>(h2, stats + 256, g2, b2, wpk + 299008, hX, stats + 512);
  k_group<<<NPTS, 256, 0, stream>>>(hX, stats + 512, g3, b3, gnorm, wpk, wb, alpha,
                                    ln1g, ln1b, ln2g, ln2b, outp + (size_t)NB*NS*3);
}